// Round 1
// baseline (2183.134 us; speedup 1.0000x reference)
//
#include <hip/hip_runtime.h>

typedef unsigned short u16;
typedef unsigned int u32;
typedef __bf16 bf16x8 __attribute__((ext_vector_type(8)));
typedef float f32x4 __attribute__((ext_vector_type(4)));
typedef u16 u16x8 __attribute__((ext_vector_type(8)));

// ---------------- helpers ----------------
__device__ __forceinline__ u16 f2bf(float f) {
    union { float f; u32 u; } v; v.f = f;
    u32 r = v.u + 0x7fffu + ((v.u >> 16) & 1u);
    return (u16)(r >> 16);
}
__device__ __forceinline__ float bf2f(u16 h) {
    union { u32 u; float f; } v; v.u = ((u32)h) << 16;
    return v.f;
}
__device__ __forceinline__ void async16(u16* lds, const u16* g) {
    __builtin_amdgcn_global_load_lds(
        (const __attribute__((address_space(1))) void*)g,
        (__attribute__((address_space(3))) void*)lds, 16, 0, 0);
}

// token index (window space) -> source/dest row in (B, 56, 56) raster order
__device__ __forceinline__ size_t win_to_img_row(int td) {
    int wb = td / 49, t = td - wb * 49;
    int bb = wb >> 6, w = wb & 63;
    int wh = w >> 3, ww = w & 7;
    int th = t / 7, tw = t - th * 7;
    int oh = wh * 7 + th + 3; if (oh >= 56) oh -= 56;
    int ow = ww * 7 + tw + 3; if (ow >= 56) ow -= 56;
    return ((size_t)bb * 3136 + oh * 56 + ow);
}

// ---------------- fp32 -> bf16 weight convert ----------------
__global__ void cvt_kernel(const float* __restrict__ s, u16* __restrict__ d, int n) {
    int i = blockIdx.x * 256 + threadIdx.x;
    if (i < n) d[i] = f2bf(s[i]);
}

// ---------------- LayerNorm (wave per token), optional shift+window gather ----------------
template <bool SHIFT>
__global__ __launch_bounds__(256) void ln_kernel(
    const float* __restrict__ src, const float* __restrict__ g,
    const float* __restrict__ b, u16* __restrict__ dst)
{
    const int lane = threadIdx.x & 63;
    const int td = blockIdx.x * 4 + (threadIdx.x >> 6);
    size_t so;
    if (SHIFT) so = win_to_img_row(td) * 512;
    else       so = (size_t)td * 512;

    const float4* px = (const float4*)(src + so);
    float4 v0 = px[lane * 2], v1 = px[lane * 2 + 1];
    float a[8] = {v0.x, v0.y, v0.z, v0.w, v1.x, v1.y, v1.z, v1.w};
    float s = 0.f, q = 0.f;
#pragma unroll
    for (int e = 0; e < 8; ++e) { s += a[e]; q += a[e] * a[e]; }
#pragma unroll
    for (int m = 32; m; m >>= 1) { s += __shfl_xor(s, m); q += __shfl_xor(q, m); }
    float mean = s * (1.f / 512.f);
    float var  = q * (1.f / 512.f) - mean * mean;
    float rstd = rsqrtf(var + 1e-5f);
    const int c0 = lane * 8;
    u16x8 o;
#pragma unroll
    for (int e = 0; e < 8; ++e)
        o[e] = f2bf((a[e] - mean) * rstd * g[c0 + e] + b[c0 + e]);
    *(u16x8*)(dst + (size_t)td * 512 + c0) = o;
}

// ---------------- bf16 MFMA GEMM:  C[m,n] = sum_k A[m,k] * W[n,k] + bias[n] ----------------
// EPI: 0 = store bf16, 1 = gelu + store bf16, 2 = proj scatter (+residual -> fp32 out),
//      3 = fp32 out += val
template <int EPI>
__global__ __launch_bounds__(256) void gemm_bt(
    const u16* __restrict__ A, const u16* __restrict__ W,
    const float* __restrict__ bias, int M, int N, int K,
    void* __restrict__ Cout, const float* __restrict__ Xres)
{
    __shared__ __align__(16) u16 sA[128 * 32];
    __shared__ __align__(16) u16 sB[128 * 32];
    const int tid = threadIdx.x;
    const int wave = tid >> 6, lane = tid & 63;
    const int nbn = N >> 7;
    const int bm = blockIdx.x / nbn, bn = blockIdx.x - bm * nbn;
    const int m0 = bm << 7, n0 = bn << 7;
    const int wm = wave >> 1, wn = wave & 1;
    const int ln = lane & 15, kq = lane >> 4;

    // staging: each wave covers 32 rows (two 16-row wave-loads of 1KB)
    const int srow = wave * 32 + (lane >> 2);
    const int scol = (lane & 3) << 3;
    const u16* gA = A + (size_t)(m0 + srow) * K + scol;
    const u16* gB = W + (size_t)(n0 + srow) * K + scol;
    u16* lA = &sA[wave * 32 * 32];
    u16* lB = &sB[wave * 32 * 32];

    f32x4 acc[4][4] = {};

    for (int k0 = 0; k0 < K; k0 += 32) {
        async16(lA,           gA);
        async16(lA + 16 * 32, gA + (size_t)16 * K);
        async16(lB,           gB);
        async16(lB + 16 * 32, gB + (size_t)16 * K);
        gA += 32; gB += 32;
        __syncthreads();   // compiler drains vmcnt before barrier

        bf16x8 af[4], bfr[4];
#pragma unroll
        for (int i = 0; i < 4; ++i)
            af[i] = *(const bf16x8*)&sA[(wm * 64 + i * 16 + ln) * 32 + kq * 8];
#pragma unroll
        for (int j = 0; j < 4; ++j)
            bfr[j] = *(const bf16x8*)&sB[(wn * 64 + j * 16 + ln) * 32 + kq * 8];
#pragma unroll
        for (int i = 0; i < 4; ++i)
#pragma unroll
            for (int j = 0; j < 4; ++j)
                acc[i][j] = __builtin_amdgcn_mfma_f32_16x16x32_bf16(af[i], bfr[j], acc[i][j], 0, 0, 0);
        __syncthreads();
    }

#pragma unroll
    for (int i = 0; i < 4; ++i) {
#pragma unroll
        for (int r = 0; r < 4; ++r) {
            const int row = m0 + wm * 64 + i * 16 + kq * 4 + r;
            size_t obase;
            if (EPI == 2) obase = win_to_img_row(row) * 512;
            else          obase = (size_t)row * N;
#pragma unroll
            for (int j = 0; j < 4; ++j) {
                const int col = n0 + wn * 64 + j * 16 + ln;
                float val = acc[i][j][r] + bias[col];
                if (EPI == 0) {
                    ((u16*)Cout)[obase + col] = f2bf(val);
                } else if (EPI == 1) {
                    val = 0.5f * val * (1.0f + erff(val * 0.70710678118654752f));
                    ((u16*)Cout)[obase + col] = f2bf(val);
                } else if (EPI == 2) {
                    ((float*)Cout)[obase + col] = Xres[obase + col] + val;
                } else {
                    ((float*)Cout)[obase + col] += val;
                }
            }
        }
    }
}

// ---------------- windowed attention, one block per (window-batch, head) ----------------
__global__ __launch_bounds__(256) void attn_kernel(
    const u16* __restrict__ qkv, const float* __restrict__ relb,
    u16* __restrict__ outp, int wbOff)
{
    __shared__ float sq[49][33];
    __shared__ float sk[49][33];
    __shared__ float sv[49][32];
    __shared__ float sS[49][49];
    const int tid = threadIdx.x;
    const int wbl = blockIdx.x >> 4;
    const int head = blockIdx.x & 15;
    const int wbg = wbl + wbOff;
    const int w = wbg & 63;
    const size_t qbase = (size_t)wbl * 49 * 1536 + head * 32;

    for (int e = tid; e < 49 * 32; e += 256) {
        int r = e >> 5, d = e & 31;
        size_t a = qbase + (size_t)r * 1536 + d;
        sq[r][d] = bf2f(qkv[a]) * 0.1767766952966369f;
        sk[r][d] = bf2f(qkv[a + 512]);
        sv[r][d] = bf2f(qkv[a + 1024]);
    }
    __syncthreads();

    const int wh = w >> 3, ww = w & 7;
    for (int e = tid; e < 49 * 49; e += 256) {
        int r = e / 49, c = e - r * 49;
        float s = 0.f;
#pragma unroll
        for (int d = 0; d < 32; ++d) s += sq[r][d] * sk[c][d];
        int rh = r / 7, rw = r - rh * 7;
        int ch = c / 7, cw = c - ch * 7;
        s += relb[((rh - ch + 6) * 13 + (rw - cw + 6)) * 16 + head];
        int pr = wh * 7 + rh, qr = ww * 7 + rw;
        int pc = wh * 7 + ch, qc = ww * 7 + cw;
        int lr = (pr < 49 ? 0 : (pr < 53 ? 1 : 2)) * 3 + (qr < 49 ? 0 : (qr < 53 ? 1 : 2));
        int lc = (pc < 49 ? 0 : (pc < 53 ? 1 : 2)) * 3 + (qc < 49 ? 0 : (qc < 53 ? 1 : 2));
        if (lr != lc) s -= 100.f;
        sS[r][c] = s;
    }
    __syncthreads();

    if (tid < 49) {
        float mx = -1e30f;
        for (int c = 0; c < 49; ++c) mx = fmaxf(mx, sS[tid][c]);
        float sum = 0.f;
        for (int c = 0; c < 49; ++c) { float e = __expf(sS[tid][c] - mx); sS[tid][c] = e; sum += e; }
        float inv = 1.f / sum;
        for (int c = 0; c < 49; ++c) sS[tid][c] *= inv;
    }
    __syncthreads();

    for (int e = tid; e < 49 * 32; e += 256) {
        int r = e >> 5, d = e & 31;
        float o = 0.f;
        for (int c = 0; c < 49; ++c) o += sS[r][c] * sv[c][d];
        outp[((size_t)(wbg * 49 + r)) * 512 + head * 32 + d] = f2bf(o);
    }
}

// ---------------- launch ----------------
extern "C" void kernel_launch(void* const* d_in, const int* in_sizes, int n_in,
                              void* d_out, int out_size, void* d_ws, size_t ws_size,
                              hipStream_t stream)
{
    (void)in_sizes; (void)n_in; (void)out_size; (void)ws_size;
    const float* x     = (const float*)d_in[0];
    const float* n1g   = (const float*)d_in[1];
    const float* n1b   = (const float*)d_in[2];
    const float* qkvw  = (const float*)d_in[3];
    const float* qkvb  = (const float*)d_in[4];
    const float* relb  = (const float*)d_in[5];
    const float* projw = (const float*)d_in[6];
    const float* projb = (const float*)d_in[7];
    const float* n2g   = (const float*)d_in[8];
    const float* n2b   = (const float*)d_in[9];
    const float* fc1w  = (const float*)d_in[10];
    const float* fc1b  = (const float*)d_in[11];
    const float* fc2w  = (const float*)d_in[12];
    const float* fc2b  = (const float*)d_in[13];
    float* out = (float*)d_out;

    char* p = (char*)d_ws;
    u16* wq   = (u16*)p; p += (size_t)786432  * 2;
    u16* wp   = (u16*)p; p += (size_t)262144  * 2;
    u16* w1   = (u16*)p; p += (size_t)1048576 * 2;
    u16* w2   = (u16*)p; p += (size_t)1048576 * 2;
    u16* bufA = (u16*)p; p += (size_t)100352 * 512 * 2;   // yw / attn_out / h_ln2
    u16* bufB = (u16*)p;                                   // qkv chunk / fc1 chunk (<= 25088*2048*2 B)

    cvt_kernel<<<3072, 256, 0, stream>>>(qkvw, wq, 786432);
    cvt_kernel<<<1024, 256, 0, stream>>>(projw, wp, 262144);
    cvt_kernel<<<4096, 256, 0, stream>>>(fc1w, w1, 1048576);
    cvt_kernel<<<4096, 256, 0, stream>>>(fc2w, w2, 1048576);

    // LN1 + shift + window partition -> bufA (bf16, window layout)
    ln_kernel<true><<<25088, 256, 0, stream>>>(x, n1g, n1b, bufA);

    // QKV + attention, 4 chunks of 512 window-batches (25088 rows)
    for (int c = 0; c < 4; ++c) {
        const u16* Ach = bufA + (size_t)c * 25088 * 512;
        gemm_bt<0><<<196 * 12, 256, 0, stream>>>(Ach, wq, qkvb, 25088, 1536, 512, bufB, nullptr);
        attn_kernel<<<512 * 16, 256, 0, stream>>>(bufB, relb, bufA, c * 512);
    }

    // proj + window-reverse + unshift + residual -> d_out (x2, fp32)
    gemm_bt<2><<<784 * 4, 256, 0, stream>>>(bufA, wp, projb, 100352, 512, 512, out, x);

    // LN2 -> bufA (bf16)
    ln_kernel<false><<<25088, 256, 0, stream>>>(out, n2g, n2b, bufA);

    // MLP, 4 chunks of 25088 rows; fc2 accumulates into d_out
    for (int c = 0; c < 4; ++c) {
        const u16* Ach = bufA + (size_t)c * 25088 * 512;
        float* Och = out + (size_t)c * 25088 * 512;
        gemm_bt<1><<<196 * 16, 256, 0, stream>>>(Ach, w1, fc1b, 25088, 2048, 512, bufB, nullptr);
        gemm_bt<3><<<196 * 4,  256, 0, stream>>>(bufB, w2, fc2b, 25088, 512, 2048, Och, nullptr);
    }
}

// Round 2
// 1732.189 us; speedup vs baseline: 1.2603x; 1.2603x over previous
//
#include <hip/hip_runtime.h>

typedef unsigned short u16;
typedef unsigned int u32;
typedef __bf16 bf16x8 __attribute__((ext_vector_type(8)));
typedef float f32x4 __attribute__((ext_vector_type(4)));
typedef u16 u16x8 __attribute__((ext_vector_type(8)));

// ---------------- helpers ----------------
__device__ __forceinline__ u16 f2bf(float f) {
    union { float f; u32 u; } v; v.f = f;
    u32 r = v.u + 0x7fffu + ((v.u >> 16) & 1u);
    return (u16)(r >> 16);
}
__device__ __forceinline__ void async16(u16* lds, const u16* g) {
    __builtin_amdgcn_global_load_lds(
        (const __attribute__((address_space(1))) void*)g,
        (__attribute__((address_space(3))) void*)lds, 16, 0, 0);
}

// token index (window space) -> source/dest row in (B, 56, 56) raster order
__device__ __forceinline__ size_t win_to_img_row(int td) {
    int wb = td / 49, t = td - wb * 49;
    int bb = wb >> 6, w = wb & 63;
    int wh = w >> 3, ww = w & 7;
    int th = t / 7, tw = t - th * 7;
    int oh = wh * 7 + th + 3; if (oh >= 56) oh -= 56;
    int ow = ww * 7 + tw + 3; if (ow >= 56) ow -= 56;
    return ((size_t)bb * 3136 + oh * 56 + ow);
}

// ---------------- fp32 -> bf16 weight convert ----------------
__global__ void cvt_kernel(const float* __restrict__ s, u16* __restrict__ d, int n) {
    int i = blockIdx.x * 256 + threadIdx.x;
    if (i < n) d[i] = f2bf(s[i]);
}

// ---------------- bias+mask table: T[cat][head][64][64] fp32 ----------------
__global__ void tbl_kernel(const float* __restrict__ relb, float* __restrict__ T) {
    int i = blockIdx.x * 256 + threadIdx.x;      // 4*16*64*64 = 262144
    int c = i & 63, r = (i >> 6) & 63, head = (i >> 12) & 15, cat = i >> 16;
    float v;
    if (c >= 49 || r >= 49) v = -1e30f;
    else {
        int rh = r / 7, rw = r - rh * 7, ch = c / 7, cw = c - ch * 7;
        v = relb[((rh - ch + 6) * 13 + (rw - cw + 6)) * 16 + head];
        int lr = ((cat & 2) ? (rh < 4 ? 1 : 2) : 0) * 3 + ((cat & 1) ? (rw < 4 ? 1 : 2) : 0);
        int lc = ((cat & 2) ? (ch < 4 ? 1 : 2) : 0) * 3 + ((cat & 1) ? (cw < 4 ? 1 : 2) : 0);
        if (lr != lc) v -= 100.f;
    }
    T[i] = v;
}

// ---------------- LayerNorm (wave per token), optional shift+window gather ----------------
template <bool SHIFT>
__global__ __launch_bounds__(256) void ln_kernel(
    const float* __restrict__ src, const float* __restrict__ g,
    const float* __restrict__ b, u16* __restrict__ dst)
{
    const int lane = threadIdx.x & 63;
    const int td = blockIdx.x * 4 + (threadIdx.x >> 6);
    size_t so;
    if (SHIFT) so = win_to_img_row(td) * 512;
    else       so = (size_t)td * 512;

    const float4* px = (const float4*)(src + so);
    float4 v0 = px[lane * 2], v1 = px[lane * 2 + 1];
    float a[8] = {v0.x, v0.y, v0.z, v0.w, v1.x, v1.y, v1.z, v1.w};
    float s = 0.f, q = 0.f;
#pragma unroll
    for (int e = 0; e < 8; ++e) { s += a[e]; q += a[e] * a[e]; }
#pragma unroll
    for (int m = 32; m; m >>= 1) { s += __shfl_xor(s, m); q += __shfl_xor(q, m); }
    float mean = s * (1.f / 512.f);
    float var  = q * (1.f / 512.f) - mean * mean;
    float rstd = rsqrtf(var + 1e-5f);
    const int c0 = lane * 8;
    u16x8 o;
#pragma unroll
    for (int e = 0; e < 8; ++e)
        o[e] = f2bf((a[e] - mean) * rstd * g[c0 + e] + b[c0 + e]);
    *(u16x8*)(dst + (size_t)td * 512 + c0) = o;
}

// ---------------- bf16 MFMA GEMM:  C[m,n] = sum_k A[m,k] * W[n,k] + bias[n] ----------------
// EPI: 0 = store bf16, 1 = gelu + store bf16, 2 = proj scatter (+residual -> fp32 out),
//      3 = fp32 out += val
template <int EPI>
__global__ __launch_bounds__(256) void gemm_bt(
    const u16* __restrict__ A, const u16* __restrict__ W,
    const float* __restrict__ bias, int M, int N, int K,
    void* __restrict__ Cout, const float* __restrict__ Xres)
{
    __shared__ __align__(16) u16 sA[128 * 32];
    __shared__ __align__(16) u16 sB[128 * 32];
    const int tid = threadIdx.x;
    const int wave = tid >> 6, lane = tid & 63;
    const int nbn = N >> 7;
    const int bm = blockIdx.x / nbn, bn = blockIdx.x - bm * nbn;
    const int m0 = bm << 7, n0 = bn << 7;
    const int wm = wave >> 1, wn = wave & 1;
    const int ln = lane & 15, kq = lane >> 4;

    const int srow = wave * 32 + (lane >> 2);
    const int scol = (lane & 3) << 3;
    const u16* gA = A + (size_t)(m0 + srow) * K + scol;
    const u16* gB = W + (size_t)(n0 + srow) * K + scol;
    u16* lA = &sA[wave * 32 * 32];
    u16* lB = &sB[wave * 32 * 32];

    f32x4 acc[4][4] = {};

    for (int k0 = 0; k0 < K; k0 += 32) {
        async16(lA,           gA);
        async16(lA + 16 * 32, gA + (size_t)16 * K);
        async16(lB,           gB);
        async16(lB + 16 * 32, gB + (size_t)16 * K);
        gA += 32; gB += 32;
        __syncthreads();

        bf16x8 af[4], bfr[4];
#pragma unroll
        for (int i = 0; i < 4; ++i)
            af[i] = *(const bf16x8*)&sA[(wm * 64 + i * 16 + ln) * 32 + kq * 8];
#pragma unroll
        for (int j = 0; j < 4; ++j)
            bfr[j] = *(const bf16x8*)&sB[(wn * 64 + j * 16 + ln) * 32 + kq * 8];
#pragma unroll
        for (int i = 0; i < 4; ++i)
#pragma unroll
            for (int j = 0; j < 4; ++j)
                acc[i][j] = __builtin_amdgcn_mfma_f32_16x16x32_bf16(af[i], bfr[j], acc[i][j], 0, 0, 0);
        __syncthreads();
    }

#pragma unroll
    for (int i = 0; i < 4; ++i) {
#pragma unroll
        for (int r = 0; r < 4; ++r) {
            const int row = m0 + wm * 64 + i * 16 + kq * 4 + r;
            size_t obase;
            if (EPI == 2) obase = win_to_img_row(row) * 512;
            else          obase = (size_t)row * N;
#pragma unroll
            for (int j = 0; j < 4; ++j) {
                const int col = n0 + wn * 64 + j * 16 + ln;
                float val = acc[i][j][r] + bias[col];
                if (EPI == 0) {
                    ((u16*)Cout)[obase + col] = f2bf(val);
                } else if (EPI == 1) {
                    val = 0.5f * val * (1.0f + erff(val * 0.70710678118654752f));
                    ((u16*)Cout)[obase + col] = f2bf(val);
                } else if (EPI == 2) {
                    ((float*)Cout)[obase + col] = Xres[obase + col] + val;
                } else {
                    ((float*)Cout)[obase + col] += val;
                }
            }
        }
    }
}

// ---------------- MFMA windowed attention ----------------
// Block = 4 waves = one (window-batch, head). Wave w owns output row-tile w (rows 16w..16w+15).
// S = Q K^T via 16x16x32 MFMA (K=hd=32), softmax in-register (unnormalized P; 1/sum folded
// into the output store), PV via MFMA with V staged transposed.
__global__ __launch_bounds__(256) void attn_kernel(
    const u16* __restrict__ qkv, const float* __restrict__ tbl,
    u16* __restrict__ outp, int wbOff)
{
    __shared__ __align__(16) u16 qb[64][40];
    __shared__ __align__(16) u16 kb[64][40];
    __shared__ __align__(16) u16 vt[32][72];
    __shared__ __align__(16) u16 pb[64][72];

    const int tid = threadIdx.x;
    const int lane = tid & 63, wv = tid >> 6;
    const int wbl = blockIdx.x >> 4, head = blockIdx.x & 15;
    const int wbg = wbl + wbOff;
    const int w = wbg & 63;
    const int cat = (((w >> 3) == 7) ? 2 : 0) + (((w & 7) == 7) ? 1 : 0);
    const size_t base = (size_t)wbl * 49 * 1536 + head * 32;

    const u16x8 zz = {};
    // zero K pad rows 49..63 (so S cols >=49 are finite; table then masks them)
    for (int e = tid; e < 75; e += 256) {
        int r = 49 + e / 5, c8 = e % 5;
        *(u16x8*)&kb[r][c8 * 8] = zz;
    }
    // zero V^T pad cols 48..71 (P pad cols are exactly 0; need 0*0, not 0*NaN)
    for (int e = tid; e < 96; e += 256) {
        int d = e / 3, c8 = e % 3;
        *(u16x8*)&vt[d][48 + c8 * 8] = zz;
    }
    // stage Q, K (row-major) and V (transposed)
    for (int e3 = tid; e3 < 588; e3 += 256) {
        int sel = e3 / 196, e = e3 - sel * 196;
        int r = e >> 2, c8 = e & 3;
        u16x8 v = *(const u16x8*)&qkv[base + (size_t)r * 1536 + sel * 512 + c8 * 8];
        if (sel == 0)      *(u16x8*)&qb[r][c8 * 8] = v;
        else if (sel == 1) *(u16x8*)&kb[r][c8 * 8] = v;
        else {
#pragma unroll
            for (int j = 0; j < 8; ++j) vt[c8 * 8 + j][r] = v[j];
        }
    }
    __syncthreads();

    const int ln = lane & 15, kq = lane >> 4;

    // ---- S = Q K^T, row-tile wv, 4 col-tiles ----
    bf16x8 a = *(const bf16x8*)&qb[wv * 16 + ln][kq * 8];
    f32x4 acc[4] = {};
#pragma unroll
    for (int j = 0; j < 4; ++j) {
        bf16x8 b = *(const bf16x8*)&kb[j * 16 + ln][kq * 8];
        acc[j] = __builtin_amdgcn_mfma_f32_16x16x32_bf16(a, b, acc[j], 0, 0, 0);
    }

    // ---- bias/mask + scale + softmax (rows kq*4+t of tile wv) ----
    const float* tb = tbl + (((cat * 16 + head) * 64) + wv * 16 + kq * 4) * 64 + ln;
    const float sc = 0.1767766952966369f;
    float inv[4];
#pragma unroll
    for (int t = 0; t < 4; ++t) {
        float v0 = acc[0][t] * sc + tb[t * 64];
        float v1 = acc[1][t] * sc + tb[t * 64 + 16];
        float v2 = acc[2][t] * sc + tb[t * 64 + 32];
        float v3 = acc[3][t] * sc + tb[t * 64 + 48];
        float m = fmaxf(fmaxf(v0, v1), fmaxf(v2, v3));
#pragma unroll
        for (int d = 1; d < 16; d <<= 1) m = fmaxf(m, __shfl_xor(m, d));
        v0 = __expf(v0 - m); v1 = __expf(v1 - m);
        v2 = __expf(v2 - m); v3 = __expf(v3 - m);
        float s = v0 + v1 + v2 + v3;
#pragma unroll
        for (int d = 1; d < 16; d <<= 1) s += __shfl_xor(s, d);
        inv[t] = 1.f / s;
        const int row = wv * 16 + kq * 4 + t;
        pb[row][ln]      = f2bf(v0);
        pb[row][ln + 16] = f2bf(v1);
        pb[row][ln + 32] = f2bf(v2);
        pb[row][ln + 48] = f2bf(v3);
    }

    // ---- O = P V (wave reads only its own P rows -> no barrier needed) ----
    f32x4 o[2] = {};
#pragma unroll
    for (int ks = 0; ks < 2; ++ks) {
        bf16x8 pa = *(const bf16x8*)&pb[wv * 16 + ln][ks * 32 + kq * 8];
#pragma unroll
        for (int j2 = 0; j2 < 2; ++j2) {
            bf16x8 vb = *(const bf16x8*)&vt[j2 * 16 + ln][ks * 32 + kq * 8];
            o[j2] = __builtin_amdgcn_mfma_f32_16x16x32_bf16(pa, vb, o[j2], 0, 0, 0);
        }
    }

    // ---- store (normalize by inv here; same lane computed inv for these rows) ----
#pragma unroll
    for (int t = 0; t < 4; ++t) {
        const int r = wv * 16 + kq * 4 + t;
        if (r < 49) {
            const size_t ob = ((size_t)(wbg * 49 + r)) * 512 + head * 32;
#pragma unroll
            for (int j2 = 0; j2 < 2; ++j2)
                outp[ob + j2 * 16 + ln] = f2bf(o[j2][t] * inv[t]);
        }
    }
}

// ---------------- launch ----------------
extern "C" void kernel_launch(void* const* d_in, const int* in_sizes, int n_in,
                              void* d_out, int out_size, void* d_ws, size_t ws_size,
                              hipStream_t stream)
{
    (void)in_sizes; (void)n_in; (void)out_size; (void)ws_size;
    const float* x     = (const float*)d_in[0];
    const float* n1g   = (const float*)d_in[1];
    const float* n1b   = (const float*)d_in[2];
    const float* qkvw  = (const float*)d_in[3];
    const float* qkvb  = (const float*)d_in[4];
    const float* relb  = (const float*)d_in[5];
    const float* projw = (const float*)d_in[6];
    const float* projb = (const float*)d_in[7];
    const float* n2g   = (const float*)d_in[8];
    const float* n2b   = (const float*)d_in[9];
    const float* fc1w  = (const float*)d_in[10];
    const float* fc1b  = (const float*)d_in[11];
    const float* fc2w  = (const float*)d_in[12];
    const float* fc2b  = (const float*)d_in[13];
    float* out = (float*)d_out;

    char* p = (char*)d_ws;
    u16* wq   = (u16*)p; p += (size_t)786432  * 2;
    u16* wp   = (u16*)p; p += (size_t)262144  * 2;
    u16* w1   = (u16*)p; p += (size_t)1048576 * 2;
    u16* w2   = (u16*)p; p += (size_t)1048576 * 2;
    u16* bufA = (u16*)p; p += (size_t)100352 * 512 * 2;   // yw / attn_out / h_ln2
    u16* bufB = (u16*)p;                                   // qkv chunk / fc1 chunk
    // bias table lives in bufB's tail: beyond qkv chunk (38.5M u16), before fc1 use
    float* tbl = (float*)(bufB + (size_t)41943040);

    cvt_kernel<<<3072, 256, 0, stream>>>(qkvw, wq, 786432);
    cvt_kernel<<<1024, 256, 0, stream>>>(projw, wp, 262144);
    cvt_kernel<<<4096, 256, 0, stream>>>(fc1w, w1, 1048576);
    cvt_kernel<<<4096, 256, 0, stream>>>(fc2w, w2, 1048576);
    tbl_kernel<<<1024, 256, 0, stream>>>(relb, tbl);

    // LN1 + shift + window partition -> bufA (bf16, window layout)
    ln_kernel<true><<<25088, 256, 0, stream>>>(x, n1g, n1b, bufA);

    // QKV + attention, 4 chunks of 512 window-batches (25088 rows)
    for (int c = 0; c < 4; ++c) {
        const u16* Ach = bufA + (size_t)c * 25088 * 512;
        gemm_bt<0><<<196 * 12, 256, 0, stream>>>(Ach, wq, qkvb, 25088, 1536, 512, bufB, nullptr);
        attn_kernel<<<512 * 16, 256, 0, stream>>>(bufB, tbl, bufA, c * 512);
    }

    // proj + window-reverse + unshift + residual -> d_out (x2, fp32)
    gemm_bt<2><<<784 * 4, 256, 0, stream>>>(bufA, wp, projb, 100352, 512, 512, out, x);

    // LN2 -> bufA (bf16)
    ln_kernel<false><<<25088, 256, 0, stream>>>(out, n2g, n2b, bufA);

    // MLP, 4 chunks of 25088 rows; fc2 accumulates into d_out
    for (int c = 0; c < 4; ++c) {
        const u16* Ach = bufA + (size_t)c * 25088 * 512;
        float* Och = out + (size_t)c * 25088 * 512;
        gemm_bt<1><<<196 * 16, 256, 0, stream>>>(Ach, w1, fc1b, 25088, 2048, 512, bufB, nullptr);
        gemm_bt<3><<<196 * 4,  256, 0, stream>>>(bufB, w2, fc2b, 25088, 512, 2048, Och, nullptr);
    }
}

// Round 3
// 1521.376 us; speedup vs baseline: 1.4350x; 1.1386x over previous
//
#include <hip/hip_runtime.h>

typedef unsigned short u16;
typedef unsigned int u32;
typedef __bf16 bf16x8 __attribute__((ext_vector_type(8)));
typedef float f32x4 __attribute__((ext_vector_type(4)));
typedef u16 u16x8 __attribute__((ext_vector_type(8)));

// ---------------- helpers ----------------
__device__ __forceinline__ u16 f2bf(float f) {
    union { float f; u32 u; } v; v.f = f;
    u32 r = v.u + 0x7fffu + ((v.u >> 16) & 1u);
    return (u16)(r >> 16);
}
__device__ __forceinline__ void async16(u16* lds, const u16* g) {
    __builtin_amdgcn_global_load_lds(
        (const __attribute__((address_space(1))) void*)g,
        (__attribute__((address_space(3))) void*)lds, 16, 0, 0);
}

// token index (window space) -> source/dest row in (B, 56, 56) raster order
__device__ __forceinline__ size_t win_to_img_row(int td) {
    int wb = td / 49, t = td - wb * 49;
    int bb = wb >> 6, w = wb & 63;
    int wh = w >> 3, ww = w & 7;
    int th = t / 7, tw = t - th * 7;
    int oh = wh * 7 + th + 3; if (oh >= 56) oh -= 56;
    int ow = ww * 7 + tw + 3; if (ow >= 56) ow -= 56;
    return ((size_t)bb * 3136 + oh * 56 + ow);
}

// ---------------- fp32 -> bf16 weight convert ----------------
__global__ void cvt_kernel(const float* __restrict__ s, u16* __restrict__ d, int n) {
    int i = blockIdx.x * 256 + threadIdx.x;
    if (i < n) d[i] = f2bf(s[i]);
}

// ---------------- bias+mask table: T[cat][head][64][64] fp32 ----------------
__global__ void tbl_kernel(const float* __restrict__ relb, float* __restrict__ T) {
    int i = blockIdx.x * 256 + threadIdx.x;      // 4*16*64*64 = 262144
    int c = i & 63, r = (i >> 6) & 63, head = (i >> 12) & 15, cat = i >> 16;
    float v;
    if (c >= 49 || r >= 49) v = -1e30f;
    else {
        int rh = r / 7, rw = r - rh * 7, ch = c / 7, cw = c - ch * 7;
        v = relb[((rh - ch + 6) * 13 + (rw - cw + 6)) * 16 + head];
        int lr = ((cat & 2) ? (rh < 4 ? 1 : 2) : 0) * 3 + ((cat & 1) ? (rw < 4 ? 1 : 2) : 0);
        int lc = ((cat & 2) ? (ch < 4 ? 1 : 2) : 0) * 3 + ((cat & 1) ? (cw < 4 ? 1 : 2) : 0);
        if (lr != lc) v -= 100.f;
    }
    T[i] = v;
}

// ---------------- LayerNorm (wave per token), optional shift+window gather ----------------
template <bool SHIFT>
__global__ __launch_bounds__(256) void ln_kernel(
    const float* __restrict__ src, const float* __restrict__ g,
    const float* __restrict__ b, u16* __restrict__ dst)
{
    const int lane = threadIdx.x & 63;
    const int td = blockIdx.x * 4 + (threadIdx.x >> 6);
    size_t so;
    if (SHIFT) so = win_to_img_row(td) * 512;
    else       so = (size_t)td * 512;

    const float4* px = (const float4*)(src + so);
    float4 v0 = px[lane * 2], v1 = px[lane * 2 + 1];
    float a[8] = {v0.x, v0.y, v0.z, v0.w, v1.x, v1.y, v1.z, v1.w};
    float s = 0.f, q = 0.f;
#pragma unroll
    for (int e = 0; e < 8; ++e) { s += a[e]; q += a[e] * a[e]; }
#pragma unroll
    for (int m = 32; m; m >>= 1) { s += __shfl_xor(s, m); q += __shfl_xor(q, m); }
    float mean = s * (1.f / 512.f);
    float var  = q * (1.f / 512.f) - mean * mean;
    float rstd = rsqrtf(var + 1e-5f);
    const int c0 = lane * 8;
    u16x8 o;
#pragma unroll
    for (int e = 0; e < 8; ++e)
        o[e] = f2bf((a[e] - mean) * rstd * g[c0 + e] + b[c0 + e]);
    *(u16x8*)(dst + (size_t)td * 512 + c0) = o;
}

// ---------------- 256x256 8-wave deep-pipelined bf16 GEMM ----------------
// C[m,n] = sum_k A[m,k] * W[n,k] + bias[n].  BK=32, 4 LDS buffers, counted vmcnt.
// Waves: 2 (M) x 4 (N); per-wave output 128x64 = acc[8][4] f32x4.
// LDS tile [256][32] bf16 with 16B-quantum XOR swizzle: slot ^= row&3
// (staged via linear-dest global_load_lds + inverse-swizzled global source).
// EPI: 0 = store bf16, 1 = gelu + store bf16, 2 = proj scatter (+residual -> fp32 out),
//      3 = fp32 out += val
template <int EPI>
__global__ __launch_bounds__(512, 2) void gemm2(
    const u16* __restrict__ A, const u16* __restrict__ W,
    const float* __restrict__ bias, int M, int N, int K,
    void* __restrict__ Cout, const float* __restrict__ Xres)
{
    __shared__ __align__(16) u16 sA[4 * 8192];
    __shared__ __align__(16) u16 sB[4 * 8192];
    const int tid = threadIdx.x;
    const int lane = tid & 63, wv = tid >> 6;
    const int wr = wv >> 2, wc = wv & 3;
    const int ln = lane & 15, kq = lane >> 4;
    const int nbn = N >> 8;
    const int bm = blockIdx.x / nbn, bn = blockIdx.x - bm * nbn;
    const int m0 = bm << 8, n0 = bn << 8;

    // staging source (per-thread): row 0..127 within half, inverse-swizzled 16B slot
    const int srow = tid >> 2;
    const int scol = ((tid & 3) ^ (srow & 3)) << 3;            // elems
    const u16* gA = A + (size_t)(m0 + srow) * K + scol;
    const u16* gB = W + (size_t)(n0 + srow) * K + scol;
    const size_t rowK128 = (size_t)128 * K;
    const int ldst = wv << 9;                                   // wave-uniform LDS dest (elems)

    // swizzled read offsets (row&3 == ln&3 since frag rows step by 16)
    const int aoff = ((wr << 7) + ln) * 32 + ((kq ^ (ln & 3)) << 3);
    const int boff = ((wc << 6) + ln) * 32 + ((kq ^ (ln & 3)) << 3);

    const int nkt = K >> 5;
    f32x4 acc[8][4] = {};

    // ---- prologue: stage tiles 0,1,2 (4 units each, in-order) ----
#pragma unroll
    for (int t = 0; t < 3; ++t) {
        const u16* pA = gA + t * 32;
        const u16* pB = gB + t * 32;
        u16* dA = sA + t * 8192 + ldst;
        u16* dB = sB + t * 8192 + ldst;
        async16(dA, pA);
        async16(dA + 4096, pA + rowK128);
        async16(dB, pB);
        async16(dB + 4096, pB + rowK128);
    }
    asm volatile("s_waitcnt vmcnt(8)" ::: "memory");
    __builtin_amdgcn_s_barrier();

    for (int t = 0; t < nkt; ++t) {
        const int buf = t & 3;
        const u16* la = sA + buf * 8192;
        const u16* lb = sB + buf * 8192;
        const bool st = (t + 3) < nkt;
        const int sbuf = (t + 3) & 3;
        const u16* pA = gA + (size_t)(t + 3) * 32;
        const u16* pB = gB + (size_t)(t + 3) * 32;

        // ---------- phase A: quadrants m=0..3 ----------
        bf16x8 bf[4], af[4];
#pragma unroll
        for (int n = 0; n < 4; ++n) bf[n] = *(const bf16x8*)(lb + boff + n * 512);
#pragma unroll
        for (int m = 0; m < 4; ++m) af[m] = *(const bf16x8*)(la + aoff + m * 512);
        if (st) {
            u16* dA = sA + sbuf * 8192 + ldst;
            async16(dA, pA);
            async16(dA + 4096, pA + rowK128);
        }
        __builtin_amdgcn_s_barrier();
        asm volatile("s_waitcnt lgkmcnt(0)" ::: "memory");
        __builtin_amdgcn_sched_barrier(0);
        __builtin_amdgcn_s_setprio(1);
#pragma unroll
        for (int m = 0; m < 4; ++m)
#pragma unroll
            for (int n = 0; n < 4; ++n)
                acc[m][n] = __builtin_amdgcn_mfma_f32_16x16x32_bf16(af[m], bf[n], acc[m][n], 0, 0, 0);
        __builtin_amdgcn_s_setprio(0);
        __builtin_amdgcn_s_barrier();

        // ---------- phase B: quadrants m=4..7 ----------
#pragma unroll
        for (int m = 0; m < 4; ++m) af[m] = *(const bf16x8*)(la + aoff + (m + 4) * 512);
        if (st) {
            u16* dB = sB + sbuf * 8192 + ldst;
            async16(dB, pB);
            async16(dB + 4096, pB + rowK128);
        }
        __builtin_amdgcn_s_barrier();
        asm volatile("s_waitcnt lgkmcnt(0)" ::: "memory");
        __builtin_amdgcn_sched_barrier(0);
        __builtin_amdgcn_s_setprio(1);
#pragma unroll
        for (int m = 0; m < 4; ++m)
#pragma unroll
            for (int n = 0; n < 4; ++n)
                acc[m + 4][n] = __builtin_amdgcn_mfma_f32_16x16x32_bf16(af[m], bf[n], acc[m + 4][n], 0, 0, 0);
        __builtin_amdgcn_s_setprio(0);
        // counted vmcnt: next tile's 4 units must have landed; keep the rest in flight
        if (st)                asm volatile("s_waitcnt vmcnt(8)" ::: "memory");
        else if (t + 2 < nkt)  asm volatile("s_waitcnt vmcnt(4)" ::: "memory");
        else if (t + 1 < nkt)  asm volatile("s_waitcnt vmcnt(0)" ::: "memory");
        __builtin_amdgcn_s_barrier();
    }

    // ---------- epilogue ----------
    float bs[4];
#pragma unroll
    for (int n = 0; n < 4; ++n) bs[n] = bias[n0 + wc * 64 + n * 16 + ln];
#pragma unroll
    for (int m = 0; m < 8; ++m) {
#pragma unroll
        for (int r = 0; r < 4; ++r) {
            const int row = m0 + wr * 128 + m * 16 + kq * 4 + r;
            size_t obase;
            if (EPI == 2) obase = win_to_img_row(row) * 512;
            else          obase = (size_t)row * N;
#pragma unroll
            for (int n = 0; n < 4; ++n) {
                const int col = n0 + wc * 64 + n * 16 + ln;
                float val = acc[m][n][r] + bs[n];
                if (EPI == 0) {
                    ((u16*)Cout)[obase + col] = f2bf(val);
                } else if (EPI == 1) {
                    val = 0.5f * val * (1.0f + erff(val * 0.70710678118654752f));
                    ((u16*)Cout)[obase + col] = f2bf(val);
                } else if (EPI == 2) {
                    ((float*)Cout)[obase + col] = Xres[obase + col] + val;
                } else {
                    ((float*)Cout)[obase + col] += val;
                }
            }
        }
    }
}

// ---------------- MFMA windowed attention ----------------
__global__ __launch_bounds__(256) void attn_kernel(
    const u16* __restrict__ qkv, const float* __restrict__ tbl,
    u16* __restrict__ outp, int wbOff)
{
    __shared__ __align__(16) u16 qb[64][40];
    __shared__ __align__(16) u16 kb[64][40];
    __shared__ __align__(16) u16 vt[32][72];
    __shared__ __align__(16) u16 pb[64][72];

    const int tid = threadIdx.x;
    const int lane = tid & 63, wv = tid >> 6;
    const int wbl = blockIdx.x >> 4, head = blockIdx.x & 15;
    const int wbg = wbl + wbOff;
    const int w = wbg & 63;
    const int cat = (((w >> 3) == 7) ? 2 : 0) + (((w & 7) == 7) ? 1 : 0);
    const size_t base = (size_t)wbl * 49 * 1536 + head * 32;

    const u16x8 zz = {};
    for (int e = tid; e < 75; e += 256) {
        int r = 49 + e / 5, c8 = e % 5;
        *(u16x8*)&kb[r][c8 * 8] = zz;
    }
    for (int e = tid; e < 96; e += 256) {
        int d = e / 3, c8 = e % 3;
        *(u16x8*)&vt[d][48 + c8 * 8] = zz;
    }
    for (int e3 = tid; e3 < 588; e3 += 256) {
        int sel = e3 / 196, e = e3 - sel * 196;
        int r = e >> 2, c8 = e & 3;
        u16x8 v = *(const u16x8*)&qkv[base + (size_t)r * 1536 + sel * 512 + c8 * 8];
        if (sel == 0)      *(u16x8*)&qb[r][c8 * 8] = v;
        else if (sel == 1) *(u16x8*)&kb[r][c8 * 8] = v;
        else {
#pragma unroll
            for (int j = 0; j < 8; ++j) vt[c8 * 8 + j][r] = v[j];
        }
    }
    __syncthreads();

    const int ln = lane & 15, kq = lane >> 4;

    bf16x8 a = *(const bf16x8*)&qb[wv * 16 + ln][kq * 8];
    f32x4 acc[4] = {};
#pragma unroll
    for (int j = 0; j < 4; ++j) {
        bf16x8 b = *(const bf16x8*)&kb[j * 16 + ln][kq * 8];
        acc[j] = __builtin_amdgcn_mfma_f32_16x16x32_bf16(a, b, acc[j], 0, 0, 0);
    }

    const float* tb = tbl + (((cat * 16 + head) * 64) + wv * 16 + kq * 4) * 64 + ln;
    const float sc = 0.1767766952966369f;
    float inv[4];
#pragma unroll
    for (int t = 0; t < 4; ++t) {
        float v0 = acc[0][t] * sc + tb[t * 64];
        float v1 = acc[1][t] * sc + tb[t * 64 + 16];
        float v2 = acc[2][t] * sc + tb[t * 64 + 32];
        float v3 = acc[3][t] * sc + tb[t * 64 + 48];
        float m = fmaxf(fmaxf(v0, v1), fmaxf(v2, v3));
#pragma unroll
        for (int d = 1; d < 16; d <<= 1) m = fmaxf(m, __shfl_xor(m, d));
        v0 = __expf(v0 - m); v1 = __expf(v1 - m);
        v2 = __expf(v2 - m); v3 = __expf(v3 - m);
        float s = v0 + v1 + v2 + v3;
#pragma unroll
        for (int d = 1; d < 16; d <<= 1) s += __shfl_xor(s, d);
        inv[t] = 1.f / s;
        const int row = wv * 16 + kq * 4 + t;
        pb[row][ln]      = f2bf(v0);
        pb[row][ln + 16] = f2bf(v1);
        pb[row][ln + 32] = f2bf(v2);
        pb[row][ln + 48] = f2bf(v3);
    }

    f32x4 o[2] = {};
#pragma unroll
    for (int ks = 0; ks < 2; ++ks) {
        bf16x8 pa = *(const bf16x8*)&pb[wv * 16 + ln][ks * 32 + kq * 8];
#pragma unroll
        for (int j2 = 0; j2 < 2; ++j2) {
            bf16x8 vb = *(const bf16x8*)&vt[j2 * 16 + ln][ks * 32 + kq * 8];
            o[j2] = __builtin_amdgcn_mfma_f32_16x16x32_bf16(pa, vb, o[j2], 0, 0, 0);
        }
    }

#pragma unroll
    for (int t = 0; t < 4; ++t) {
        const int r = wv * 16 + kq * 4 + t;
        if (r < 49) {
            const size_t ob = ((size_t)(wbg * 49 + r)) * 512 + head * 32;
#pragma unroll
            for (int j2 = 0; j2 < 2; ++j2)
                outp[ob + j2 * 16 + ln] = f2bf(o[j2][t] * inv[t]);
        }
    }
}

// ---------------- launch ----------------
extern "C" void kernel_launch(void* const* d_in, const int* in_sizes, int n_in,
                              void* d_out, int out_size, void* d_ws, size_t ws_size,
                              hipStream_t stream)
{
    (void)in_sizes; (void)n_in; (void)out_size;
    const float* x     = (const float*)d_in[0];
    const float* n1g   = (const float*)d_in[1];
    const float* n1b   = (const float*)d_in[2];
    const float* qkvw  = (const float*)d_in[3];
    const float* qkvb  = (const float*)d_in[4];
    const float* relb  = (const float*)d_in[5];
    const float* projw = (const float*)d_in[6];
    const float* projb = (const float*)d_in[7];
    const float* n2g   = (const float*)d_in[8];
    const float* n2b   = (const float*)d_in[9];
    const float* fc1w  = (const float*)d_in[10];
    const float* fc1b  = (const float*)d_in[11];
    const float* fc2w  = (const float*)d_in[12];
    const float* fc2b  = (const float*)d_in[13];
    float* out = (float*)d_out;

    char* p = (char*)d_ws;
    u16* wq    = (u16*)p; p += (size_t)786432  * 2;
    u16* wp    = (u16*)p; p += (size_t)262144  * 2;
    u16* w1    = (u16*)p; p += (size_t)1048576 * 2;
    u16* w2    = (u16*)p; p += (size_t)1048576 * 2;
    float* tbl = (float*)p; p += (size_t)262144 * 4;
    u16* bufA  = (u16*)p; p += (size_t)100352 * 512 * 2;   // yw / attn_out / h_ln2
    u16* bufB  = (u16*)p;                                   // qkv chunk / fc1 chunk

    // choose chunking by available workspace: 2 chunks needs bufB = 50176*2048*2 B
    const size_t fixed = ((size_t)786432 + 262144 + 1048576 + 1048576) * 2
                       + (size_t)262144 * 4 + (size_t)100352 * 512 * 2;
    const int nch = (ws_size >= fixed + (size_t)50176 * 2048 * 2) ? 2 : 4;
    const int chM = 100352 / nch;          // rows per chunk (multiple of 256 and 49)
    const int chWB = chM / 49;             // window-batches per chunk

    cvt_kernel<<<3072, 256, 0, stream>>>(qkvw, wq, 786432);
    cvt_kernel<<<1024, 256, 0, stream>>>(projw, wp, 262144);
    cvt_kernel<<<4096, 256, 0, stream>>>(fc1w, w1, 1048576);
    cvt_kernel<<<4096, 256, 0, stream>>>(fc2w, w2, 1048576);
    tbl_kernel<<<1024, 256, 0, stream>>>(relb, tbl);

    // LN1 + shift + window partition -> bufA (bf16, window layout)
    ln_kernel<true><<<25088, 256, 0, stream>>>(x, n1g, n1b, bufA);

    // QKV + attention, chunked
    for (int c = 0; c < nch; ++c) {
        const u16* Ach = bufA + (size_t)c * chM * 512;
        gemm2<0><<<(chM >> 8) * 6, 512, 0, stream>>>(Ach, wq, qkvb, chM, 1536, 512, bufB, nullptr);
        attn_kernel<<<chWB * 16, 256, 0, stream>>>(bufB, tbl, bufA, c * chWB);
    }

    // proj + window-reverse + unshift + residual -> d_out (x2, fp32)
    gemm2<2><<<392 * 2, 512, 0, stream>>>(bufA, wp, projb, 100352, 512, 512, out, x);

    // LN2 -> bufA (bf16)
    ln_kernel<false><<<25088, 256, 0, stream>>>(out, n2g, n2b, bufA);

    // MLP, chunked; fc2 accumulates into d_out
    for (int c = 0; c < nch; ++c) {
        const u16* Ach = bufA + (size_t)c * chM * 512;
        float* Och = out + (size_t)c * chM * 512;
        gemm2<1><<<(chM >> 8) * 8, 512, 0, stream>>>(Ach, w1, fc1b, chM, 2048, 512, bufB, nullptr);
        gemm2<3><<<(chM >> 8) * 2, 512, 0, stream>>>(bufB, w2, fc2b, chM, 512, 2048, Och, nullptr);
    }
}

// Round 4
// 1452.209 us; speedup vs baseline: 1.5033x; 1.0476x over previous
//
#include <hip/hip_runtime.h>

typedef unsigned short u16;
typedef unsigned int u32;
typedef __bf16 bf16x8 __attribute__((ext_vector_type(8)));
typedef float f32x4 __attribute__((ext_vector_type(4)));
typedef u16 u16x8 __attribute__((ext_vector_type(8)));

// ---------------- helpers ----------------
__device__ __forceinline__ u16 f2bf(float f) {
    union { float f; u32 u; } v; v.f = f;
    u32 r = v.u + 0x7fffu + ((v.u >> 16) & 1u);
    return (u16)(r >> 16);
}
__device__ __forceinline__ void async16(u16* lds, const u16* g) {
    __builtin_amdgcn_global_load_lds(
        (const __attribute__((address_space(1))) void*)g,
        (__attribute__((address_space(3))) void*)lds, 16, 0, 0);
}

// token index (window space) -> source/dest row in (B, 56, 56) raster order
__device__ __forceinline__ size_t win_to_img_row(int td) {
    int wb = td / 49, t = td - wb * 49;
    int bb = wb >> 6, w = wb & 63;
    int wh = w >> 3, ww = w & 7;
    int th = t / 7, tw = t - th * 7;
    int oh = wh * 7 + th + 3; if (oh >= 56) oh -= 56;
    int ow = ww * 7 + tw + 3; if (ow >= 56) ow -= 56;
    return ((size_t)bb * 3136 + oh * 56 + ow);
}

// ---------------- fp32 -> bf16 weight convert ----------------
__global__ void cvt_kernel(const float* __restrict__ s, u16* __restrict__ d, int n) {
    int i = blockIdx.x * 256 + threadIdx.x;
    if (i < n) d[i] = f2bf(s[i]);
}

// ---------------- bias+mask table: T[cat][head][64][64] fp32 ----------------
__global__ void tbl_kernel(const float* __restrict__ relb, float* __restrict__ T) {
    int i = blockIdx.x * 256 + threadIdx.x;      // 4*16*64*64 = 262144
    int c = i & 63, r = (i >> 6) & 63, head = (i >> 12) & 15, cat = i >> 16;
    float v;
    if (c >= 49 || r >= 49) v = -1e30f;
    else {
        int rh = r / 7, rw = r - rh * 7, ch = c / 7, cw = c - ch * 7;
        v = relb[((rh - ch + 6) * 13 + (rw - cw + 6)) * 16 + head];
        int lr = ((cat & 2) ? (rh < 4 ? 1 : 2) : 0) * 3 + ((cat & 1) ? (rw < 4 ? 1 : 2) : 0);
        int lc = ((cat & 2) ? (ch < 4 ? 1 : 2) : 0) * 3 + ((cat & 1) ? (cw < 4 ? 1 : 2) : 0);
        if (lr != lc) v -= 100.f;
    }
    T[i] = v;
}

// ---------------- LayerNorm (wave per token), optional shift+window gather ----------------
template <bool SHIFT>
__global__ __launch_bounds__(256) void ln_kernel(
    const float* __restrict__ src, const float* __restrict__ g,
    const float* __restrict__ b, u16* __restrict__ dst)
{
    const int lane = threadIdx.x & 63;
    const int td = blockIdx.x * 4 + (threadIdx.x >> 6);
    size_t so;
    if (SHIFT) so = win_to_img_row(td) * 512;
    else       so = (size_t)td * 512;

    const float4* px = (const float4*)(src + so);
    float4 v0 = px[lane * 2], v1 = px[lane * 2 + 1];
    float a[8] = {v0.x, v0.y, v0.z, v0.w, v1.x, v1.y, v1.z, v1.w};
    float s = 0.f, q = 0.f;
#pragma unroll
    for (int e = 0; e < 8; ++e) { s += a[e]; q += a[e] * a[e]; }
#pragma unroll
    for (int m = 32; m; m >>= 1) { s += __shfl_xor(s, m); q += __shfl_xor(q, m); }
    float mean = s * (1.f / 512.f);
    float var  = q * (1.f / 512.f) - mean * mean;
    float rstd = rsqrtf(var + 1e-5f);
    const int c0 = lane * 8;
    u16x8 o;
#pragma unroll
    for (int e = 0; e < 8; ++e)
        o[e] = f2bf((a[e] - mean) * rstd * g[c0 + e] + b[c0 + e]);
    *(u16x8*)(dst + (size_t)td * 512 + c0) = o;
}

// ---------------- 256x128 4-wave pipelined bf16 GEMM ----------------
// C[m,n] = sum_k A[m,k] * W[n,k] + bias[n].  BK=32, 3 LDS buffers (72KB -> 2 blocks/CU),
// counted vmcnt(6): stage t+2 while computing t, tile t+1 in flight across the barrier.
// Waves: 2M x 2N; per-wave output 128x64 = acc[8][4] (FLOP/LDS-byte = 43).
// Swizzle: LDS[row][q] holds global quantum q ^ ((row>>1)&3)  ->  bank tuple (row&1, q)
// distinct over 8 consecutive rows => 2-way max on ds_read_b128 (free).
// XCD swizzle: hw block b -> logical (b&7)*(nwg/8) + b>>3 (grids all %8==0).
// EPI: 0 = store bf16, 1 = gelu + store bf16, 2 = proj scatter (+residual -> fp32 out),
//      3 = fp32 out += val
template <int EPI>
__global__ __launch_bounds__(256, 2) void gemm3(
    const u16* __restrict__ A, const u16* __restrict__ W,
    const float* __restrict__ bias, int M, int N, int K,
    void* __restrict__ Cout, const float* __restrict__ Xres)
{
    __shared__ __align__(16) u16 sA[3][8192];   // 256 x 32
    __shared__ __align__(16) u16 sB[3][4096];   // 128 x 32
    const int tid = threadIdx.x;
    const int lane = tid & 63, wv = tid >> 6;
    const int wm = wv >> 1, wn = wv & 1;
    const int ln = lane & 15, kq = lane >> 4;
    const int nbn = N >> 7;
    const int nwg = gridDim.x;
    const int wgid = (blockIdx.x & 7) * (nwg >> 3) + (blockIdx.x >> 3);
    const int bm = wgid / nbn, bn = wgid - bm * nbn;
    const int m0 = bm << 8, n0 = bn << 7;

    // staging source: 4 threads per row, 16B slot (tid&3) holds global quantum (tid&3)^((row>>1)&3)
    const int srow = tid >> 2;
    const int scol = (((tid & 3) ^ ((tid >> 3) & 3)) << 3);
    const u16* gA = A + (size_t)(m0 + srow) * K + scol;
    const u16* gB = W + (size_t)(n0 + srow) * K + scol;
    const size_t row64 = (size_t)64 * K;

    // swizzled fragment read offsets (row>>1)&3 == (ln>>1)&3 for all fragment rows
    const int swq = (kq ^ ((ln >> 1) & 3)) << 3;
    const int aoff = (wm * 128 + ln) * 32 + swq;
    const int boff = (wn * 64 + ln) * 32 + swq;

    const int nkt = K >> 5;
    f32x4 acc[8][4] = {};

#define STAGE(tt) do { \
        u16* da = &sA[(tt) % 3][tid * 8]; \
        u16* db = &sB[(tt) % 3][tid * 8]; \
        const u16* pa = gA + (size_t)(tt) * 32; \
        const u16* pb = gB + (size_t)(tt) * 32; \
        async16(da,        pa); \
        async16(da + 2048, pa + row64); \
        async16(da + 4096, pa + 2 * row64); \
        async16(da + 6144, pa + 3 * row64); \
        async16(db,        pb); \
        async16(db + 2048, pb + row64); \
    } while (0)

    STAGE(0);
    STAGE(1);
    asm volatile("s_waitcnt vmcnt(6)" ::: "memory");
    __builtin_amdgcn_s_barrier();

    for (int t = 0; t < nkt; ++t) {
        const u16* la = sA[t % 3];
        const u16* lb = sB[t % 3];
        if (t + 2 < nkt) STAGE(t + 2);
        bf16x8 af[8], bf[4];
#pragma unroll
        for (int i = 0; i < 8; ++i) af[i] = *(const bf16x8*)(la + aoff + i * 512);
#pragma unroll
        for (int j = 0; j < 4; ++j) bf[j] = *(const bf16x8*)(lb + boff + j * 512);
        __builtin_amdgcn_s_setprio(1);
#pragma unroll
        for (int i = 0; i < 8; ++i)
#pragma unroll
            for (int j = 0; j < 4; ++j)
                acc[i][j] = __builtin_amdgcn_mfma_f32_16x16x32_bf16(af[i], bf[j], acc[i][j], 0, 0, 0);
        __builtin_amdgcn_s_setprio(0);
        if (t + 2 < nkt)      asm volatile("s_waitcnt vmcnt(6)" ::: "memory");
        else if (t + 1 < nkt) asm volatile("s_waitcnt vmcnt(0)" ::: "memory");
        if (t + 1 < nkt) __builtin_amdgcn_s_barrier();
    }
#undef STAGE

    // ---------- epilogue ----------
    float bs[4];
#pragma unroll
    for (int n = 0; n < 4; ++n) bs[n] = bias[n0 + wn * 64 + n * 16 + ln];
#pragma unroll
    for (int i = 0; i < 8; ++i) {
#pragma unroll
        for (int r = 0; r < 4; ++r) {
            const int row = m0 + wm * 128 + i * 16 + kq * 4 + r;
            size_t obase;
            if (EPI == 2) obase = win_to_img_row(row) * 512;
            else          obase = (size_t)row * N;
#pragma unroll
            for (int n = 0; n < 4; ++n) {
                const int col = n0 + wn * 64 + n * 16 + ln;
                float val = acc[i][n][r] + bs[n];
                if (EPI == 0) {
                    ((u16*)Cout)[obase + col] = f2bf(val);
                } else if (EPI == 1) {
                    val = 0.5f * val * (1.0f + erff(val * 0.70710678118654752f));
                    ((u16*)Cout)[obase + col] = f2bf(val);
                } else if (EPI == 2) {
                    ((float*)Cout)[obase + col] = Xres[obase + col] + val;
                } else {
                    ((float*)Cout)[obase + col] += val;
                }
            }
        }
    }
}

// ---------------- MFMA windowed attention ----------------
__global__ __launch_bounds__(256) void attn_kernel(
    const u16* __restrict__ qkv, const float* __restrict__ tbl,
    u16* __restrict__ outp, int wbOff)
{
    __shared__ __align__(16) u16 qb[64][40];
    __shared__ __align__(16) u16 kb[64][40];
    __shared__ __align__(16) u16 vt[32][72];
    __shared__ __align__(16) u16 pb[64][72];

    const int tid = threadIdx.x;
    const int lane = tid & 63, wv = tid >> 6;
    const int wbl = blockIdx.x >> 4, head = blockIdx.x & 15;
    const int wbg = wbl + wbOff;
    const int w = wbg & 63;
    const int cat = (((w >> 3) == 7) ? 2 : 0) + (((w & 7) == 7) ? 1 : 0);
    const size_t base = (size_t)wbl * 49 * 1536 + head * 32;

    const u16x8 zz = {};
    for (int e = tid; e < 75; e += 256) {
        int r = 49 + e / 5, c8 = e % 5;
        *(u16x8*)&kb[r][c8 * 8] = zz;
    }
    for (int e = tid; e < 96; e += 256) {
        int d = e / 3, c8 = e % 3;
        *(u16x8*)&vt[d][48 + c8 * 8] = zz;
    }
    for (int e3 = tid; e3 < 588; e3 += 256) {
        int sel = e3 / 196, e = e3 - sel * 196;
        int r = e >> 2, c8 = e & 3;
        u16x8 v = *(const u16x8*)&qkv[base + (size_t)r * 1536 + sel * 512 + c8 * 8];
        if (sel == 0)      *(u16x8*)&qb[r][c8 * 8] = v;
        else if (sel == 1) *(u16x8*)&kb[r][c8 * 8] = v;
        else {
#pragma unroll
            for (int j = 0; j < 8; ++j) vt[c8 * 8 + j][r] = v[j];
        }
    }
    __syncthreads();

    const int ln = lane & 15, kq = lane >> 4;

    bf16x8 a = *(const bf16x8*)&qb[wv * 16 + ln][kq * 8];
    f32x4 acc[4] = {};
#pragma unroll
    for (int j = 0; j < 4; ++j) {
        bf16x8 b = *(const bf16x8*)&kb[j * 16 + ln][kq * 8];
        acc[j] = __builtin_amdgcn_mfma_f32_16x16x32_bf16(a, b, acc[j], 0, 0, 0);
    }

    const float* tb = tbl + (((cat * 16 + head) * 64) + wv * 16 + kq * 4) * 64 + ln;
    const float sc = 0.1767766952966369f;
    float inv[4];
#pragma unroll
    for (int t = 0; t < 4; ++t) {
        float v0 = acc[0][t] * sc + tb[t * 64];
        float v1 = acc[1][t] * sc + tb[t * 64 + 16];
        float v2 = acc[2][t] * sc + tb[t * 64 + 32];
        float v3 = acc[3][t] * sc + tb[t * 64 + 48];
        float m = fmaxf(fmaxf(v0, v1), fmaxf(v2, v3));
#pragma unroll
        for (int d = 1; d < 16; d <<= 1) m = fmaxf(m, __shfl_xor(m, d));
        v0 = __expf(v0 - m); v1 = __expf(v1 - m);
        v2 = __expf(v2 - m); v3 = __expf(v3 - m);
        float s = v0 + v1 + v2 + v3;
#pragma unroll
        for (int d = 1; d < 16; d <<= 1) s += __shfl_xor(s, d);
        inv[t] = 1.f / s;
        const int row = wv * 16 + kq * 4 + t;
        pb[row][ln]      = f2bf(v0);
        pb[row][ln + 16] = f2bf(v1);
        pb[row][ln + 32] = f2bf(v2);
        pb[row][ln + 48] = f2bf(v3);
    }

    f32x4 o[2] = {};
#pragma unroll
    for (int ks = 0; ks < 2; ++ks) {
        bf16x8 pa = *(const bf16x8*)&pb[wv * 16 + ln][ks * 32 + kq * 8];
#pragma unroll
        for (int j2 = 0; j2 < 2; ++j2) {
            bf16x8 vb = *(const bf16x8*)&vt[j2 * 16 + ln][ks * 32 + kq * 8];
            o[j2] = __builtin_amdgcn_mfma_f32_16x16x32_bf16(pa, vb, o[j2], 0, 0, 0);
        }
    }

#pragma unroll
    for (int t = 0; t < 4; ++t) {
        const int r = wv * 16 + kq * 4 + t;
        if (r < 49) {
            const size_t ob = ((size_t)(wbg * 49 + r)) * 512 + head * 32;
#pragma unroll
            for (int j2 = 0; j2 < 2; ++j2)
                outp[ob + j2 * 16 + ln] = f2bf(o[j2][t] * inv[t]);
        }
    }
}

// ---------------- launch ----------------
extern "C" void kernel_launch(void* const* d_in, const int* in_sizes, int n_in,
                              void* d_out, int out_size, void* d_ws, size_t ws_size,
                              hipStream_t stream)
{
    (void)in_sizes; (void)n_in; (void)out_size;
    const float* x     = (const float*)d_in[0];
    const float* n1g   = (const float*)d_in[1];
    const float* n1b   = (const float*)d_in[2];
    const float* qkvw  = (const float*)d_in[3];
    const float* qkvb  = (const float*)d_in[4];
    const float* relb  = (const float*)d_in[5];
    const float* projw = (const float*)d_in[6];
    const float* projb = (const float*)d_in[7];
    const float* n2g   = (const float*)d_in[8];
    const float* n2b   = (const float*)d_in[9];
    const float* fc1w  = (const float*)d_in[10];
    const float* fc1b  = (const float*)d_in[11];
    const float* fc2w  = (const float*)d_in[12];
    const float* fc2b  = (const float*)d_in[13];
    float* out = (float*)d_out;

    char* p = (char*)d_ws;
    u16* wq    = (u16*)p; p += (size_t)786432  * 2;
    u16* wp    = (u16*)p; p += (size_t)262144  * 2;
    u16* w1    = (u16*)p; p += (size_t)1048576 * 2;
    u16* w2    = (u16*)p; p += (size_t)1048576 * 2;
    float* tbl = (float*)p; p += (size_t)262144 * 4;
    u16* bufA  = (u16*)p; p += (size_t)100352 * 512 * 2;   // yw / attn_out / h_ln2
    u16* bufB  = (u16*)p;                                   // qkv chunk / fc1 chunk

    const size_t fixed = ((size_t)786432 + 262144 + 1048576 + 1048576) * 2
                       + (size_t)262144 * 4 + (size_t)100352 * 512 * 2;
    const int nch = (ws_size >= fixed + (size_t)50176 * 2048 * 2) ? 2 : 4;
    const int chM = 100352 / nch;          // rows per chunk (multiple of 256 and 49)
    const int chWB = chM / 49;             // window-batches per chunk

    cvt_kernel<<<3072, 256, 0, stream>>>(qkvw, wq, 786432);
    cvt_kernel<<<1024, 256, 0, stream>>>(projw, wp, 262144);
    cvt_kernel<<<4096, 256, 0, stream>>>(fc1w, w1, 1048576);
    cvt_kernel<<<4096, 256, 0, stream>>>(fc2w, w2, 1048576);
    tbl_kernel<<<1024, 256, 0, stream>>>(relb, tbl);

    // LN1 + shift + window partition -> bufA (bf16, window layout)
    ln_kernel<true><<<25088, 256, 0, stream>>>(x, n1g, n1b, bufA);

    // QKV + attention, chunked
    for (int c = 0; c < nch; ++c) {
        const u16* Ach = bufA + (size_t)c * chM * 512;
        gemm3<0><<<(chM >> 8) * 12, 256, 0, stream>>>(Ach, wq, qkvb, chM, 1536, 512, bufB, nullptr);
        attn_kernel<<<chWB * 16, 256, 0, stream>>>(bufB, tbl, bufA, c * chWB);
    }

    // proj + window-reverse + unshift + residual -> d_out (x2, fp32)
    gemm3<2><<<392 * 4, 256, 0, stream>>>(bufA, wp, projb, 100352, 512, 512, out, x);

    // LN2 -> bufA (bf16)
    ln_kernel<false><<<25088, 256, 0, stream>>>(out, n2g, n2b, bufA);

    // MLP, chunked; fc2 accumulates into d_out
    for (int c = 0; c < nch; ++c) {
        const u16* Ach = bufA + (size_t)c * chM * 512;
        float* Och = out + (size_t)c * chM * 512;
        gemm3<1><<<(chM >> 8) * 16, 256, 0, stream>>>(Ach, w1, fc1b, chM, 2048, 512, bufB, nullptr);
        gemm3<3><<<(chM >> 8) * 4,  256, 0, stream>>>(bufB, w2, fc2b, chM, 512, 2048, Och, nullptr);
    }
}

// Round 5
// 1364.510 us; speedup vs baseline: 1.5999x; 1.0643x over previous
//
#include <hip/hip_runtime.h>

typedef unsigned short u16;
typedef unsigned int u32;
typedef __bf16 bf16x8 __attribute__((ext_vector_type(8)));
typedef float f32x4 __attribute__((ext_vector_type(4)));
typedef u16 u16x8 __attribute__((ext_vector_type(8)));

// ---------------- helpers ----------------
__device__ __forceinline__ u16 f2bf(float f) {
    union { float f; u32 u; } v; v.f = f;
    u32 r = v.u + 0x7fffu + ((v.u >> 16) & 1u);
    return (u16)(r >> 16);
}
__device__ __forceinline__ void async16(u16* lds, const u16* g) {
    __builtin_amdgcn_global_load_lds(
        (const __attribute__((address_space(1))) void*)g,
        (__attribute__((address_space(3))) void*)lds, 16, 0, 0);
}

// token index (window space) -> source/dest row in (B, 56, 56) raster order
__device__ __forceinline__ size_t win_to_img_row(int td) {
    int wb = td / 49, t = td - wb * 49;
    int bb = wb >> 6, w = wb & 63;
    int wh = w >> 3, ww = w & 7;
    int th = t / 7, tw = t - th * 7;
    int oh = wh * 7 + th + 3; if (oh >= 56) oh -= 56;
    int ow = ww * 7 + tw + 3; if (ow >= 56) ow -= 56;
    return ((size_t)bb * 3136 + oh * 56 + ow);
}

// ---------------- fp32 -> bf16 weight convert ----------------
__global__ void cvt_kernel(const float* __restrict__ s, u16* __restrict__ d, int n) {
    int i = blockIdx.x * 256 + threadIdx.x;
    if (i < n) d[i] = f2bf(s[i]);
}

// ---------------- bias+mask table: T[cat][head][64][64] fp32 ----------------
__global__ void tbl_kernel(const float* __restrict__ relb, float* __restrict__ T) {
    int i = blockIdx.x * 256 + threadIdx.x;      // 4*16*64*64 = 262144
    int c = i & 63, r = (i >> 6) & 63, head = (i >> 12) & 15, cat = i >> 16;
    float v;
    if (c >= 49 || r >= 49) v = -1e30f;
    else {
        int rh = r / 7, rw = r - rh * 7, ch = c / 7, cw = c - ch * 7;
        v = relb[((rh - ch + 6) * 13 + (rw - cw + 6)) * 16 + head];
        int lr = ((cat & 2) ? (rh < 4 ? 1 : 2) : 0) * 3 + ((cat & 1) ? (rw < 4 ? 1 : 2) : 0);
        int lc = ((cat & 2) ? (ch < 4 ? 1 : 2) : 0) * 3 + ((cat & 1) ? (cw < 4 ? 1 : 2) : 0);
        if (lr != lc) v -= 100.f;
    }
    T[i] = v;
}

// ---------------- LayerNorm (wave per token), optional shift+window gather ----------------
template <bool SHIFT>
__global__ __launch_bounds__(256) void ln_kernel(
    const float* __restrict__ src, const float* __restrict__ g,
    const float* __restrict__ b, u16* __restrict__ dst)
{
    const int lane = threadIdx.x & 63;
    const int td = blockIdx.x * 4 + (threadIdx.x >> 6);
    size_t so;
    if (SHIFT) so = win_to_img_row(td) * 512;
    else       so = (size_t)td * 512;

    const float4* px = (const float4*)(src + so);
    float4 v0 = px[lane * 2], v1 = px[lane * 2 + 1];
    float a[8] = {v0.x, v0.y, v0.z, v0.w, v1.x, v1.y, v1.z, v1.w};
    float s = 0.f, q = 0.f;
#pragma unroll
    for (int e = 0; e < 8; ++e) { s += a[e]; q += a[e] * a[e]; }
#pragma unroll
    for (int m = 32; m; m >>= 1) { s += __shfl_xor(s, m); q += __shfl_xor(q, m); }
    float mean = s * (1.f / 512.f);
    float var  = q * (1.f / 512.f) - mean * mean;
    float rstd = rsqrtf(var + 1e-5f);
    const int c0 = lane * 8;
    u16x8 o;
#pragma unroll
    for (int e = 0; e < 8; ++e)
        o[e] = f2bf((a[e] - mean) * rstd * g[c0 + e] + b[c0 + e]);
    *(u16x8*)(dst + (size_t)td * 512 + c0) = o;
}

// ---------------- 256x128 8-wave pipelined bf16 GEMM (high occupancy) ----------------
// C[m,n] = sum_k A[m,k] * W[n,k] + bias[n].  BK=32, 3 LDS buffers (72KB -> 2 blocks/CU),
// counted vmcnt(3): stage t+2 while computing t, tile t+1 in flight across the barrier.
// Waves: 4M x 2N; per-wave output 64x64 = acc[4][4] (64 VGPR) -> launch_bounds(512,4)
// => 4 waves/SIMD, 16 waves/CU (50% occupancy).
// Swizzle: LDS[row][q] holds global quantum q ^ ((row>>1)&3); verified conflict-free (R4).
// XCD swizzle: hw block b -> (b&7)*(nwg/8) + b>>3 when nwg%8==0.
// EPI: 0 = store bf16, 1 = gelu + store bf16, 2 = proj scatter (+residual -> fp32 out),
//      3 = fp32 out += val
template <int EPI>
__global__ __launch_bounds__(512, 4) void gemm4(
    const u16* __restrict__ A, const u16* __restrict__ W,
    const float* __restrict__ bias, int M, int N, int K,
    void* __restrict__ Cout, const float* __restrict__ Xres)
{
    __shared__ __align__(16) u16 sA[3][8192];   // 256 x 32
    __shared__ __align__(16) u16 sB[3][4096];   // 128 x 32
    const int tid = threadIdx.x;
    const int lane = tid & 63, wv = tid >> 6;
    const int wm = wv >> 1, wn = wv & 1;
    const int ln = lane & 15, kq = lane >> 4;
    const int nbn = N >> 7;
    const int nwg = gridDim.x;
    const int wgid = ((nwg & 7) == 0) ? ((blockIdx.x & 7) * (nwg >> 3) + (blockIdx.x >> 3))
                                      : blockIdx.x;
    const int bm = wgid / nbn, bn = wgid - bm * nbn;
    const int m0 = bm << 8, n0 = bn << 7;

    // staging source: 4 threads per row, slot (tid&3) holds global quantum (tid&3)^((row>>1)&3)
    const int srow = tid >> 2;                       // 0..127
    const int scol = ((tid & 3) ^ ((tid >> 3) & 3)) << 3;
    const u32 aOff = (u32)(m0 + srow) * (u32)K + scol;
    const u32 bOff = (u32)(n0 + srow) * (u32)K + scol;
    const u32 row128 = (u32)128 * (u32)K;

    // swizzled fragment read offsets ((row>>1)&3 == (ln>>1)&3 for all fragment rows)
    const int swq = (kq ^ ((ln >> 1) & 3)) << 3;
    const int aoff = (wm * 64 + ln) * 32 + swq;
    const int boff = (wn * 64 + ln) * 32 + swq;

    const int nkt = K >> 5;
    f32x4 acc[4][4] = {};

#define STAGE(tt) do { \
        u16* da = &sA[(tt) % 3][tid * 8]; \
        u16* db = &sB[(tt) % 3][tid * 8]; \
        const u32 ko = (u32)(tt) * 32; \
        async16(da,        A + (aOff + ko)); \
        async16(da + 4096, A + (aOff + row128 + ko)); \
        async16(db,        W + (bOff + ko)); \
    } while (0)

    STAGE(0);
    STAGE(1);
    asm volatile("s_waitcnt vmcnt(3)" ::: "memory");
    __builtin_amdgcn_s_barrier();

    for (int t = 0; t < nkt; ++t) {
        const u16* la = sA[t % 3];
        const u16* lb = sB[t % 3];
        if (t + 2 < nkt) STAGE(t + 2);
        bf16x8 af[4], bf[4];
#pragma unroll
        for (int i = 0; i < 4; ++i) af[i] = *(const bf16x8*)(la + aoff + i * 512);
#pragma unroll
        for (int j = 0; j < 4; ++j) bf[j] = *(const bf16x8*)(lb + boff + j * 512);
        __builtin_amdgcn_s_setprio(1);
#pragma unroll
        for (int i = 0; i < 4; ++i)
#pragma unroll
            for (int j = 0; j < 4; ++j)
                acc[i][j] = __builtin_amdgcn_mfma_f32_16x16x32_bf16(af[i], bf[j], acc[i][j], 0, 0, 0);
        __builtin_amdgcn_s_setprio(0);
        if (t + 2 < nkt)      asm volatile("s_waitcnt vmcnt(3)" ::: "memory");
        else if (t + 1 < nkt) asm volatile("s_waitcnt vmcnt(0)" ::: "memory");
        if (t + 1 < nkt) __builtin_amdgcn_s_barrier();
    }
#undef STAGE

    // ---------- epilogue ----------
    float bs[4];
#pragma unroll
    for (int n = 0; n < 4; ++n) bs[n] = bias[n0 + wn * 64 + n * 16 + ln];
#pragma unroll
    for (int i = 0; i < 4; ++i) {
#pragma unroll
        for (int r = 0; r < 4; ++r) {
            const int row = m0 + wm * 64 + i * 16 + kq * 4 + r;
            size_t obase;
            if (EPI == 2) obase = win_to_img_row(row) * 512;
            else          obase = (size_t)row * N;
#pragma unroll
            for (int n = 0; n < 4; ++n) {
                const int col = n0 + wn * 64 + n * 16 + ln;
                float val = acc[i][n][r] + bs[n];
                if (EPI == 0) {
                    ((u16*)Cout)[obase + col] = f2bf(val);
                } else if (EPI == 1) {
                    val = 0.5f * val * (1.0f + erff(val * 0.70710678118654752f));
                    ((u16*)Cout)[obase + col] = f2bf(val);
                } else if (EPI == 2) {
                    ((float*)Cout)[obase + col] = Xres[obase + col] + val;
                } else {
                    ((float*)Cout)[obase + col] += val;
                }
            }
        }
    }
}

// ---------------- MFMA windowed attention ----------------
__global__ __launch_bounds__(256) void attn_kernel(
    const u16* __restrict__ qkv, const float* __restrict__ tbl,
    u16* __restrict__ outp, int wbOff)
{
    __shared__ __align__(16) u16 qb[64][40];
    __shared__ __align__(16) u16 kb[64][40];
    __shared__ __align__(16) u16 vt[32][72];
    __shared__ __align__(16) u16 pb[64][72];

    const int tid = threadIdx.x;
    const int lane = tid & 63, wv = tid >> 6;
    const int wbl = blockIdx.x >> 4, head = blockIdx.x & 15;
    const int wbg = wbl + wbOff;
    const int w = wbg & 63;
    const int cat = (((w >> 3) == 7) ? 2 : 0) + (((w & 7) == 7) ? 1 : 0);
    const size_t base = (size_t)wbl * 49 * 1536 + head * 32;

    const u16x8 zz = {};
    for (int e = tid; e < 75; e += 256) {
        int r = 49 + e / 5, c8 = e % 5;
        *(u16x8*)&kb[r][c8 * 8] = zz;
    }
    for (int e = tid; e < 96; e += 256) {
        int d = e / 3, c8 = e % 3;
        *(u16x8*)&vt[d][48 + c8 * 8] = zz;
    }
    for (int e3 = tid; e3 < 588; e3 += 256) {
        int sel = e3 / 196, e = e3 - sel * 196;
        int r = e >> 2, c8 = e & 3;
        u16x8 v = *(const u16x8*)&qkv[base + (size_t)r * 1536 + sel * 512 + c8 * 8];
        if (sel == 0)      *(u16x8*)&qb[r][c8 * 8] = v;
        else if (sel == 1) *(u16x8*)&kb[r][c8 * 8] = v;
        else {
#pragma unroll
            for (int j = 0; j < 8; ++j) vt[c8 * 8 + j][r] = v[j];
        }
    }
    __syncthreads();

    const int ln = lane & 15, kq = lane >> 4;

    bf16x8 a = *(const bf16x8*)&qb[wv * 16 + ln][kq * 8];
    f32x4 acc[4] = {};
#pragma unroll
    for (int j = 0; j < 4; ++j) {
        bf16x8 b = *(const bf16x8*)&kb[j * 16 + ln][kq * 8];
        acc[j] = __builtin_amdgcn_mfma_f32_16x16x32_bf16(a, b, acc[j], 0, 0, 0);
    }

    const float* tb = tbl + (((cat * 16 + head) * 64) + wv * 16 + kq * 4) * 64 + ln;
    const float sc = 0.1767766952966369f;
    float inv[4];
#pragma unroll
    for (int t = 0; t < 4; ++t) {
        float v0 = acc[0][t] * sc + tb[t * 64];
        float v1 = acc[1][t] * sc + tb[t * 64 + 16];
        float v2 = acc[2][t] * sc + tb[t * 64 + 32];
        float v3 = acc[3][t] * sc + tb[t * 64 + 48];
        float m = fmaxf(fmaxf(v0, v1), fmaxf(v2, v3));
#pragma unroll
        for (int d = 1; d < 16; d <<= 1) m = fmaxf(m, __shfl_xor(m, d));
        v0 = __expf(v0 - m); v1 = __expf(v1 - m);
        v2 = __expf(v2 - m); v3 = __expf(v3 - m);
        float s = v0 + v1 + v2 + v3;
#pragma unroll
        for (int d = 1; d < 16; d <<= 1) s += __shfl_xor(s, d);
        inv[t] = 1.f / s;
        const int row = wv * 16 + kq * 4 + t;
        pb[row][ln]      = f2bf(v0);
        pb[row][ln + 16] = f2bf(v1);
        pb[row][ln + 32] = f2bf(v2);
        pb[row][ln + 48] = f2bf(v3);
    }

    f32x4 o[2] = {};
#pragma unroll
    for (int ks = 0; ks < 2; ++ks) {
        bf16x8 pa = *(const bf16x8*)&pb[wv * 16 + ln][ks * 32 + kq * 8];
#pragma unroll
        for (int j2 = 0; j2 < 2; ++j2) {
            bf16x8 vb = *(const bf16x8*)&vt[j2 * 16 + ln][ks * 32 + kq * 8];
            o[j2] = __builtin_amdgcn_mfma_f32_16x16x32_bf16(pa, vb, o[j2], 0, 0, 0);
        }
    }

#pragma unroll
    for (int t = 0; t < 4; ++t) {
        const int r = wv * 16 + kq * 4 + t;
        if (r < 49) {
            const size_t ob = ((size_t)(wbg * 49 + r)) * 512 + head * 32;
#pragma unroll
            for (int j2 = 0; j2 < 2; ++j2)
                outp[ob + j2 * 16 + ln] = f2bf(o[j2][t] * inv[t]);
        }
    }
}

// ---------------- launch ----------------
extern "C" void kernel_launch(void* const* d_in, const int* in_sizes, int n_in,
                              void* d_out, int out_size, void* d_ws, size_t ws_size,
                              hipStream_t stream)
{
    (void)in_sizes; (void)n_in; (void)out_size;
    const float* x     = (const float*)d_in[0];
    const float* n1g   = (const float*)d_in[1];
    const float* n1b   = (const float*)d_in[2];
    const float* qkvw  = (const float*)d_in[3];
    const float* qkvb  = (const float*)d_in[4];
    const float* relb  = (const float*)d_in[5];
    const float* projw = (const float*)d_in[6];
    const float* projb = (const float*)d_in[7];
    const float* n2g   = (const float*)d_in[8];
    const float* n2b   = (const float*)d_in[9];
    const float* fc1w  = (const float*)d_in[10];
    const float* fc1b  = (const float*)d_in[11];
    const float* fc2w  = (const float*)d_in[12];
    const float* fc2b  = (const float*)d_in[13];
    float* out = (float*)d_out;

    char* p = (char*)d_ws;
    u16* wq    = (u16*)p; p += (size_t)786432  * 2;
    u16* wp    = (u16*)p; p += (size_t)262144  * 2;
    u16* w1    = (u16*)p; p += (size_t)1048576 * 2;
    u16* w2    = (u16*)p; p += (size_t)1048576 * 2;
    float* tbl = (float*)p; p += (size_t)262144 * 4;
    u16* bufA  = (u16*)p; p += (size_t)100352 * 512 * 2;   // yw / attn_out / h_ln2
    u16* bufB  = (u16*)p;                                   // qkv chunk / fc1 chunk

    const size_t fixed = ((size_t)786432 + 262144 + 1048576 + 1048576) * 2
                       + (size_t)262144 * 4 + (size_t)100352 * 512 * 2;
    const int nch = (ws_size >= fixed + (size_t)50176 * 2048 * 2) ? 2 : 4;
    const int chM = 100352 / nch;          // rows per chunk (multiple of 256 and 49)
    const int chWB = chM / 49;             // window-batches per chunk

    cvt_kernel<<<3072, 256, 0, stream>>>(qkvw, wq, 786432);
    cvt_kernel<<<1024, 256, 0, stream>>>(projw, wp, 262144);
    cvt_kernel<<<4096, 256, 0, stream>>>(fc1w, w1, 1048576);
    cvt_kernel<<<4096, 256, 0, stream>>>(fc2w, w2, 1048576);
    tbl_kernel<<<1024, 256, 0, stream>>>(relb, tbl);

    // LN1 + shift + window partition -> bufA (bf16, window layout)
    ln_kernel<true><<<25088, 256, 0, stream>>>(x, n1g, n1b, bufA);

    // QKV + attention, chunked
    for (int c = 0; c < nch; ++c) {
        const u16* Ach = bufA + (size_t)c * chM * 512;
        gemm4<0><<<(chM >> 8) * 12, 512, 0, stream>>>(Ach, wq, qkvb, chM, 1536, 512, bufB, nullptr);
        attn_kernel<<<chWB * 16, 256, 0, stream>>>(bufB, tbl, bufA, c * chWB);
    }

    // proj + window-reverse + unshift + residual -> d_out (x2, fp32)
    gemm4<2><<<392 * 4, 512, 0, stream>>>(bufA, wp, projb, 100352, 512, 512, out, x);

    // LN2 -> bufA (bf16)
    ln_kernel<false><<<25088, 256, 0, stream>>>(out, n2g, n2b, bufA);

    // MLP, chunked; fc2 accumulates into d_out
    for (int c = 0; c < nch; ++c) {
        const u16* Ach = bufA + (size_t)c * chM * 512;
        float* Och = out + (size_t)c * chM * 512;
        gemm4<1><<<(chM >> 8) * 16, 512, 0, stream>>>(Ach, w1, fc1b, chM, 2048, 512, bufB, nullptr);
        gemm4<3><<<(chM >> 8) * 4,  512, 0, stream>>>(bufB, w2, fc2b, chM, 512, 2048, Och, nullptr);
    }
}

// Round 6
// 1306.491 us; speedup vs baseline: 1.6710x; 1.0444x over previous
//
#include <hip/hip_runtime.h>

typedef unsigned short u16;
typedef unsigned int u32;
typedef __bf16 bf16x8 __attribute__((ext_vector_type(8)));
typedef float f32x4 __attribute__((ext_vector_type(4)));
typedef u16 u16x8 __attribute__((ext_vector_type(8)));

// ---------------- helpers ----------------
__device__ __forceinline__ u16 f2bf(float f) {
    union { float f; u32 u; } v; v.f = f;
    u32 r = v.u + 0x7fffu + ((v.u >> 16) & 1u);
    return (u16)(r >> 16);
}
__device__ __forceinline__ void async16(u16* lds, const u16* g) {
    __builtin_amdgcn_global_load_lds(
        (const __attribute__((address_space(1))) void*)g,
        (__attribute__((address_space(3))) void*)lds, 16, 0, 0);
}

// token index (window space) -> source/dest row in (B, 56, 56) raster order
__device__ __forceinline__ size_t win_to_img_row(int td) {
    int wb = td / 49, t = td - wb * 49;
    int bb = wb >> 6, w = wb & 63;
    int wh = w >> 3, ww = w & 7;
    int th = t / 7, tw = t - th * 7;
    int oh = wh * 7 + th + 3; if (oh >= 56) oh -= 56;
    int ow = ww * 7 + tw + 3; if (ow >= 56) ow -= 56;
    return ((size_t)bb * 3136 + oh * 56 + ow);
}

// ---------------- fp32 -> bf16 weight convert ----------------
__global__ void cvt_kernel(const float* __restrict__ s, u16* __restrict__ d, int n) {
    int i = blockIdx.x * 256 + threadIdx.x;
    if (i < n) d[i] = f2bf(s[i]);
}

// ---------------- bias+mask table: T[cat][head][64][64] fp32 ----------------
__global__ void tbl_kernel(const float* __restrict__ relb, float* __restrict__ T) {
    int i = blockIdx.x * 256 + threadIdx.x;      // 4*16*64*64 = 262144
    int c = i & 63, r = (i >> 6) & 63, head = (i >> 12) & 15, cat = i >> 16;
    float v;
    if (c >= 49 || r >= 49) v = -1e30f;
    else {
        int rh = r / 7, rw = r - rh * 7, ch = c / 7, cw = c - ch * 7;
        v = relb[((rh - ch + 6) * 13 + (rw - cw + 6)) * 16 + head];
        int lr = ((cat & 2) ? (rh < 4 ? 1 : 2) : 0) * 3 + ((cat & 1) ? (rw < 4 ? 1 : 2) : 0);
        int lc = ((cat & 2) ? (ch < 4 ? 1 : 2) : 0) * 3 + ((cat & 1) ? (cw < 4 ? 1 : 2) : 0);
        if (lr != lc) v -= 100.f;
    }
    T[i] = v;
}

// ---------------- LayerNorm (wave per token), optional shift+window gather ----------------
template <bool SHIFT>
__global__ __launch_bounds__(256) void ln_kernel(
    const float* __restrict__ src, const float* __restrict__ g,
    const float* __restrict__ b, u16* __restrict__ dst)
{
    const int lane = threadIdx.x & 63;
    const int td = blockIdx.x * 4 + (threadIdx.x >> 6);
    size_t so;
    if (SHIFT) so = win_to_img_row(td) * 512;
    else       so = (size_t)td * 512;

    const float4* px = (const float4*)(src + so);
    float4 v0 = px[lane * 2], v1 = px[lane * 2 + 1];
    float a[8] = {v0.x, v0.y, v0.z, v0.w, v1.x, v1.y, v1.z, v1.w};
    float s = 0.f, q = 0.f;
#pragma unroll
    for (int e = 0; e < 8; ++e) { s += a[e]; q += a[e] * a[e]; }
#pragma unroll
    for (int m = 32; m; m >>= 1) { s += __shfl_xor(s, m); q += __shfl_xor(q, m); }
    float mean = s * (1.f / 512.f);
    float var  = q * (1.f / 512.f) - mean * mean;
    float rstd = rsqrtf(var + 1e-5f);
    const int c0 = lane * 8;
    u16x8 o;
#pragma unroll
    for (int e = 0; e < 8; ++e)
        o[e] = f2bf((a[e] - mean) * rstd * g[c0 + e] + b[c0 + e]);
    *(u16x8*)(dst + (size_t)td * 512 + c0) = o;
}

// ---------------- 256x256 8-wave 8-phase bf16 GEMM (T2+T3+T4+T5) ----------------
// C[m,n] = sum_k A[m,k]*W[n,k] + bias[n].  BK=64, 2 LDS dbufs (128 KiB), 512 thr.
// Waves 2M x 4N, per-wave 128x64, acc[8][4]. Iteration = 2 K-tiles = 8 phases;
// phase = {ds-read quadrant frags | stage 2 units | bar | lgkm(0) | prio1 16xMFMA prio0 | bar}.
// Quadrants: Q1(m0-3,n0-1) Q2(m0-3,n2-3) Q3(m4-7,n2-3) Q4(m4-7,n0-1; B re-read).
// Stage units (8KB = 64 rows x 128B, 1 load/thread): P1,P2: B(T+1); P3,P4: A(T+2);
// P5,P6: B(T+2); P7,P8: A(T+3).  vmcnt(4) at P4/P8 only (leaves newest 4 A-stages
// in flight; everything older proven landed).  Swizzle: 16B-quantum q ^= row&7
// (2 lanes/bank on ds_read_b128) via inverse-swizzled global source, linear LDS dest.
// EPI: 0 = bf16 store, 1 = gelu+bf16, 2 = proj scatter+residual->fp32, 3 = fp32 +=
template <int EPI>
__global__ __launch_bounds__(512, 2) void gemm5(
    const u16* __restrict__ A, const u16* __restrict__ W,
    const float* __restrict__ bias, int M, int N, int K,
    void* __restrict__ Cout, const float* __restrict__ Xres)
{
    __shared__ __align__(16) u16 lds[65536];   // A: [2][256][64] @0, B: [2][256][64] @32768
    const int tid = threadIdx.x;
    const int lane = tid & 63, wv = tid >> 6;
    const int wr = wv >> 2, wc = wv & 3;
    const int ln = lane & 15, kq = lane >> 4;
    const int nbn = N >> 8;
    const int nwg = gridDim.x;
    const int wgid = ((nwg & 7) == 0) ? ((blockIdx.x & 7) * (nwg >> 3) + (blockIdx.x >> 3))
                                      : blockIdx.x;
    const int bm = wgid / nbn, bn = wgid - bm * nbn;
    const int m0 = bm << 8, n0 = bn << 8;

    // staging: 8 threads per 128B row; thread's 16B slot (tid&7) sources global
    // quantum (tid&7)^((row)&7) with row = tid>>3 within the 64-row unit
    const int sq = (((tid & 7) ^ ((tid >> 3) & 7)) << 3);
    const u16* gA = A + (size_t)(m0 + (tid >> 3)) * K + sq;
    const u16* gB = W + (size_t)(n0 + (tid >> 3)) * K + sq;

    // frag read bases (element idx); frag rows r have r&7 == ln&7
    const int baseA0 = (wr * 128 + ln) * 64 + (((kq) ^ (ln & 7)) << 3);
    const int baseA1 = (wr * 128 + ln) * 64 + (((4 + kq) ^ (ln & 7)) << 3);
    const int baseB0 = 32768 + (wc * 64 + ln) * 64 + (((kq) ^ (ln & 7)) << 3);
    const int baseB1 = 32768 + (wc * 64 + ln) * 64 + (((4 + kq) ^ (ln & 7)) << 3);

#define STA(dd, u, t) async16(lds + (dd) * 16384 + (u) * 4096 + tid * 8, \
                              gA + (size_t)(u) * 64 * K + (size_t)(t) * 64)
#define STB(dd, u, t) async16(lds + 32768 + (dd) * 16384 + (u) * 4096 + tid * 8, \
                              gB + (size_t)(u) * 64 * K + (size_t)(t) * 64)
#define LDA(dd, ms, kh) (*(const bf16x8*)(lds + (dd) * 16384 + ((kh) ? baseA1 : baseA0) + (ms) * 1024))
#define LDB(dd, ns, kh) (*(const bf16x8*)(lds + (dd) * 16384 + ((kh) ? baseB1 : baseB0) + (ns) * 1024))
#define BAR  __builtin_amdgcn_s_barrier()
#define LGKM do { asm volatile("s_waitcnt lgkmcnt(0)" ::: "memory"); \
                  __builtin_amdgcn_sched_barrier(0); } while (0)

    const int nIter = K >> 7;                  // 2 K-tiles (BK=64) per iteration
    f32x4 acc[8][4] = {};
    bf16x8 af[4][2], bf[2][2];

    // ---- prologue: A(0), B(0), A(1) = 12 loads; oldest 8 must land ----
    STA(0, 0, 0); STA(0, 2, 0); STA(0, 1, 0); STA(0, 3, 0);
    STB(0, 0, 0); STB(0, 1, 0); STB(0, 2, 0); STB(0, 3, 0);
    STA(1, 0, 1); STA(1, 2, 1); STA(1, 1, 1); STA(1, 3, 1);
    asm volatile("s_waitcnt vmcnt(4)" ::: "memory");
    BAR;

    for (int it = 0; it < nIter; ++it) {
        const int T = 2 * it;
        const bool more = (it + 1 < nIter);
        // ---------------- P1: tile T (dbuf0) Q1 ----------------
#pragma unroll
        for (int ms = 0; ms < 4; ++ms) { af[ms][0] = LDA(0, ms, 0); af[ms][1] = LDA(0, ms, 1); }
#pragma unroll
        for (int nn = 0; nn < 2; ++nn) { bf[nn][0] = LDB(0, nn, 0); bf[nn][1] = LDB(0, nn, 1); }
        STB(1, 0, T + 1); STB(1, 1, T + 1);
        BAR; LGKM;
        __builtin_amdgcn_s_setprio(1);
#pragma unroll
        for (int ms = 0; ms < 4; ++ms)
#pragma unroll
            for (int nn = 0; nn < 2; ++nn) {
                acc[ms][nn] = __builtin_amdgcn_mfma_f32_16x16x32_bf16(af[ms][0], bf[nn][0], acc[ms][nn], 0, 0, 0);
                acc[ms][nn] = __builtin_amdgcn_mfma_f32_16x16x32_bf16(af[ms][1], bf[nn][1], acc[ms][nn], 0, 0, 0);
            }
        __builtin_amdgcn_s_setprio(0);
        BAR;
        // ---------------- P2: Q2 (m0-3, n2-3) ----------------
#pragma unroll
        for (int nn = 0; nn < 2; ++nn) { bf[nn][0] = LDB(0, nn + 2, 0); bf[nn][1] = LDB(0, nn + 2, 1); }
        STB(1, 2, T + 1); STB(1, 3, T + 1);
        BAR; LGKM;
        __builtin_amdgcn_s_setprio(1);
#pragma unroll
        for (int ms = 0; ms < 4; ++ms)
#pragma unroll
            for (int nn = 0; nn < 2; ++nn) {
                acc[ms][nn + 2] = __builtin_amdgcn_mfma_f32_16x16x32_bf16(af[ms][0], bf[nn][0], acc[ms][nn + 2], 0, 0, 0);
                acc[ms][nn + 2] = __builtin_amdgcn_mfma_f32_16x16x32_bf16(af[ms][1], bf[nn][1], acc[ms][nn + 2], 0, 0, 0);
            }
        __builtin_amdgcn_s_setprio(0);
        BAR;
        // ---------------- P3: Q3 (m4-7, n2-3) ----------------
#pragma unroll
        for (int ms = 0; ms < 4; ++ms) { af[ms][0] = LDA(0, ms + 4, 0); af[ms][1] = LDA(0, ms + 4, 1); }
        if (more) { STA(0, 0, T + 2); STA(0, 2, T + 2); }
        BAR; LGKM;
        __builtin_amdgcn_s_setprio(1);
#pragma unroll
        for (int ms = 0; ms < 4; ++ms)
#pragma unroll
            for (int nn = 0; nn < 2; ++nn) {
                acc[ms + 4][nn + 2] = __builtin_amdgcn_mfma_f32_16x16x32_bf16(af[ms][0], bf[nn][0], acc[ms + 4][nn + 2], 0, 0, 0);
                acc[ms + 4][nn + 2] = __builtin_amdgcn_mfma_f32_16x16x32_bf16(af[ms][1], bf[nn][1], acc[ms + 4][nn + 2], 0, 0, 0);
            }
        __builtin_amdgcn_s_setprio(0);
        BAR;
        // ---------------- P4: Q4 (m4-7, n0-1) ----------------
#pragma unroll
        for (int nn = 0; nn < 2; ++nn) { bf[nn][0] = LDB(0, nn, 0); bf[nn][1] = LDB(0, nn, 1); }
        if (more) { STA(0, 1, T + 2); STA(0, 3, T + 2); }
        BAR; LGKM;
        __builtin_amdgcn_s_setprio(1);
#pragma unroll
        for (int ms = 0; ms < 4; ++ms)
#pragma unroll
            for (int nn = 0; nn < 2; ++nn) {
                acc[ms + 4][nn] = __builtin_amdgcn_mfma_f32_16x16x32_bf16(af[ms][0], bf[nn][0], acc[ms + 4][nn], 0, 0, 0);
                acc[ms + 4][nn] = __builtin_amdgcn_mfma_f32_16x16x32_bf16(af[ms][1], bf[nn][1], acc[ms + 4][nn], 0, 0, 0);
            }
        __builtin_amdgcn_s_setprio(0);
        if (more) asm volatile("s_waitcnt vmcnt(4)" ::: "memory");
        else      asm volatile("s_waitcnt vmcnt(0)" ::: "memory");
        BAR;
        // ---------------- P5: tile T+1 (dbuf1) Q1 ----------------
#pragma unroll
        for (int ms = 0; ms < 4; ++ms) { af[ms][0] = LDA(1, ms, 0); af[ms][1] = LDA(1, ms, 1); }
#pragma unroll
        for (int nn = 0; nn < 2; ++nn) { bf[nn][0] = LDB(1, nn, 0); bf[nn][1] = LDB(1, nn, 1); }
        if (more) { STB(0, 0, T + 2); STB(0, 1, T + 2); }
        BAR; LGKM;
        __builtin_amdgcn_s_setprio(1);
#pragma unroll
        for (int ms = 0; ms < 4; ++ms)
#pragma unroll
            for (int nn = 0; nn < 2; ++nn) {
                acc[ms][nn] = __builtin_amdgcn_mfma_f32_16x16x32_bf16(af[ms][0], bf[nn][0], acc[ms][nn], 0, 0, 0);
                acc[ms][nn] = __builtin_amdgcn_mfma_f32_16x16x32_bf16(af[ms][1], bf[nn][1], acc[ms][nn], 0, 0, 0);
            }
        __builtin_amdgcn_s_setprio(0);
        BAR;
        // ---------------- P6: Q2 ----------------
#pragma unroll
        for (int nn = 0; nn < 2; ++nn) { bf[nn][0] = LDB(1, nn + 2, 0); bf[nn][1] = LDB(1, nn + 2, 1); }
        if (more) { STB(0, 2, T + 2); STB(0, 3, T + 2); }
        BAR; LGKM;
        __builtin_amdgcn_s_setprio(1);
#pragma unroll
        for (int ms = 0; ms < 4; ++ms)
#pragma unroll
            for (int nn = 0; nn < 2; ++nn) {
                acc[ms][nn + 2] = __builtin_amdgcn_mfma_f32_16x16x32_bf16(af[ms][0], bf[nn][0], acc[ms][nn + 2], 0, 0, 0);
                acc[ms][nn + 2] = __builtin_amdgcn_mfma_f32_16x16x32_bf16(af[ms][1], bf[nn][1], acc[ms][nn + 2], 0, 0, 0);
            }
        __builtin_amdgcn_s_setprio(0);
        BAR;
        // ---------------- P7: Q3 ----------------
#pragma unroll
        for (int ms = 0; ms < 4; ++ms) { af[ms][0] = LDA(1, ms + 4, 0); af[ms][1] = LDA(1, ms + 4, 1); }
        if (more) { STA(1, 0, T + 3); STA(1, 2, T + 3); }
        BAR; LGKM;
        __builtin_amdgcn_s_setprio(1);
#pragma unroll
        for (int ms = 0; ms < 4; ++ms)
#pragma unroll
            for (int nn = 0; nn < 2; ++nn) {
                acc[ms + 4][nn + 2] = __builtin_amdgcn_mfma_f32_16x16x32_bf16(af[ms][0], bf[nn][0], acc[ms + 4][nn + 2], 0, 0, 0);
                acc[ms + 4][nn + 2] = __builtin_amdgcn_mfma_f32_16x16x32_bf16(af[ms][1], bf[nn][1], acc[ms + 4][nn + 2], 0, 0, 0);
            }
        __builtin_amdgcn_s_setprio(0);
        BAR;
        // ---------------- P8: Q4 ----------------
#pragma unroll
        for (int nn = 0; nn < 2; ++nn) { bf[nn][0] = LDB(1, nn, 0); bf[nn][1] = LDB(1, nn, 1); }
        if (more) { STA(1, 1, T + 3); STA(1, 3, T + 3); }
        BAR; LGKM;
        __builtin_amdgcn_s_setprio(1);
#pragma unroll
        for (int ms = 0; ms < 4; ++ms)
#pragma unroll
            for (int nn = 0; nn < 2; ++nn) {
                acc[ms + 4][nn] = __builtin_amdgcn_mfma_f32_16x16x32_bf16(af[ms][0], bf[nn][0], acc[ms + 4][nn], 0, 0, 0);
                acc[ms + 4][nn] = __builtin_amdgcn_mfma_f32_16x16x32_bf16(af[ms][1], bf[nn][1], acc[ms + 4][nn], 0, 0, 0);
            }
        __builtin_amdgcn_s_setprio(0);
        if (more) asm volatile("s_waitcnt vmcnt(4)" ::: "memory");
        BAR;
    }
#undef STA
#undef STB
#undef LDA
#undef LDB
#undef BAR
#undef LGKM

    // ---------- epilogue ----------
    float bs[4];
#pragma unroll
    for (int n = 0; n < 4; ++n) bs[n] = bias[n0 + wc * 64 + n * 16 + ln];
#pragma unroll
    for (int i = 0; i < 8; ++i) {
#pragma unroll
        for (int r = 0; r < 4; ++r) {
            const int row = m0 + wr * 128 + i * 16 + kq * 4 + r;
            size_t obase;
            if (EPI == 2) obase = win_to_img_row(row) * 512;
            else          obase = (size_t)row * N;
#pragma unroll
            for (int n = 0; n < 4; ++n) {
                const int col = n0 + wc * 64 + n * 16 + ln;
                float val = acc[i][n][r] + bs[n];
                if (EPI == 0) {
                    ((u16*)Cout)[obase + col] = f2bf(val);
                } else if (EPI == 1) {
                    val = 0.5f * val * (1.0f + erff(val * 0.70710678118654752f));
                    ((u16*)Cout)[obase + col] = f2bf(val);
                } else if (EPI == 2) {
                    ((float*)Cout)[obase + col] = Xres[obase + col] + val;
                } else {
                    ((float*)Cout)[obase + col] += val;
                }
            }
        }
    }
}

// ---------------- MFMA windowed attention ----------------
__global__ __launch_bounds__(256) void attn_kernel(
    const u16* __restrict__ qkv, const float* __restrict__ tbl,
    u16* __restrict__ outp, int wbOff)
{
    __shared__ __align__(16) u16 qb[64][40];
    __shared__ __align__(16) u16 kb[64][40];
    __shared__ __align__(16) u16 vt[32][72];
    __shared__ __align__(16) u16 pb[64][72];

    const int tid = threadIdx.x;
    const int lane = tid & 63, wv = tid >> 6;
    const int wbl = blockIdx.x >> 4, head = blockIdx.x & 15;
    const int wbg = wbl + wbOff;
    const int w = wbg & 63;
    const int cat = (((w >> 3) == 7) ? 2 : 0) + (((w & 7) == 7) ? 1 : 0);
    const size_t base = (size_t)wbl * 49 * 1536 + head * 32;

    const u16x8 zz = {};
    for (int e = tid; e < 75; e += 256) {
        int r = 49 + e / 5, c8 = e % 5;
        *(u16x8*)&kb[r][c8 * 8] = zz;
    }
    for (int e = tid; e < 96; e += 256) {
        int d = e / 3, c8 = e % 3;
        *(u16x8*)&vt[d][48 + c8 * 8] = zz;
    }
    for (int e3 = tid; e3 < 588; e3 += 256) {
        int sel = e3 / 196, e = e3 - sel * 196;
        int r = e >> 2, c8 = e & 3;
        u16x8 v = *(const u16x8*)&qkv[base + (size_t)r * 1536 + sel * 512 + c8 * 8];
        if (sel == 0)      *(u16x8*)&qb[r][c8 * 8] = v;
        else if (sel == 1) *(u16x8*)&kb[r][c8 * 8] = v;
        else {
#pragma unroll
            for (int j = 0; j < 8; ++j) vt[c8 * 8 + j][r] = v[j];
        }
    }
    __syncthreads();

    const int ln = lane & 15, kq = lane >> 4;

    bf16x8 a = *(const bf16x8*)&qb[wv * 16 + ln][kq * 8];
    f32x4 acc[4] = {};
#pragma unroll
    for (int j = 0; j < 4; ++j) {
        bf16x8 b = *(const bf16x8*)&kb[j * 16 + ln][kq * 8];
        acc[j] = __builtin_amdgcn_mfma_f32_16x16x32_bf16(a, b, acc[j], 0, 0, 0);
    }

    const float* tb = tbl + (((cat * 16 + head) * 64) + wv * 16 + kq * 4) * 64 + ln;
    const float sc = 0.1767766952966369f;
    float inv[4];
#pragma unroll
    for (int t = 0; t < 4; ++t) {
        float v0 = acc[0][t] * sc + tb[t * 64];
        float v1 = acc[1][t] * sc + tb[t * 64 + 16];
        float v2 = acc[2][t] * sc + tb[t * 64 + 32];
        float v3 = acc[3][t] * sc + tb[t * 64 + 48];
        float m = fmaxf(fmaxf(v0, v1), fmaxf(v2, v3));
#pragma unroll
        for (int d = 1; d < 16; d <<= 1) m = fmaxf(m, __shfl_xor(m, d));
        v0 = __expf(v0 - m); v1 = __expf(v1 - m);
        v2 = __expf(v2 - m); v3 = __expf(v3 - m);
        float s = v0 + v1 + v2 + v3;
#pragma unroll
        for (int d = 1; d < 16; d <<= 1) s += __shfl_xor(s, d);
        inv[t] = 1.f / s;
        const int row = wv * 16 + kq * 4 + t;
        pb[row][ln]      = f2bf(v0);
        pb[row][ln + 16] = f2bf(v1);
        pb[row][ln + 32] = f2bf(v2);
        pb[row][ln + 48] = f2bf(v3);
    }

    f32x4 o[2] = {};
#pragma unroll
    for (int ks = 0; ks < 2; ++ks) {
        bf16x8 pa = *(const bf16x8*)&pb[wv * 16 + ln][ks * 32 + kq * 8];
#pragma unroll
        for (int j2 = 0; j2 < 2; ++j2) {
            bf16x8 vb = *(const bf16x8*)&vt[j2 * 16 + ln][ks * 32 + kq * 8];
            o[j2] = __builtin_amdgcn_mfma_f32_16x16x32_bf16(pa, vb, o[j2], 0, 0, 0);
        }
    }

#pragma unroll
    for (int t = 0; t < 4; ++t) {
        const int r = wv * 16 + kq * 4 + t;
        if (r < 49) {
            const size_t ob = ((size_t)(wbg * 49 + r)) * 512 + head * 32;
#pragma unroll
            for (int j2 = 0; j2 < 2; ++j2)
                outp[ob + j2 * 16 + ln] = f2bf(o[j2][t] * inv[t]);
        }
    }
}

// ---------------- launch ----------------
extern "C" void kernel_launch(void* const* d_in, const int* in_sizes, int n_in,
                              void* d_out, int out_size, void* d_ws, size_t ws_size,
                              hipStream_t stream)
{
    (void)in_sizes; (void)n_in; (void)out_size;
    const float* x     = (const float*)d_in[0];
    const float* n1g   = (const float*)d_in[1];
    const float* n1b   = (const float*)d_in[2];
    const float* qkvw  = (const float*)d_in[3];
    const float* qkvb  = (const float*)d_in[4];
    const float* relb  = (const float*)d_in[5];
    const float* projw = (const float*)d_in[6];
    const float* projb = (const float*)d_in[7];
    const float* n2g   = (const float*)d_in[8];
    const float* n2b   = (const float*)d_in[9];
    const float* fc1w  = (const float*)d_in[10];
    const float* fc1b  = (const float*)d_in[11];
    const float* fc2w  = (const float*)d_in[12];
    const float* fc2b  = (const float*)d_in[13];
    float* out = (float*)d_out;

    char* p = (char*)d_ws;
    u16* wq    = (u16*)p; p += (size_t)786432  * 2;
    u16* wp    = (u16*)p; p += (size_t)262144  * 2;
    u16* w1    = (u16*)p; p += (size_t)1048576 * 2;
    u16* w2    = (u16*)p; p += (size_t)1048576 * 2;
    float* tbl = (float*)p; p += (size_t)262144 * 4;
    u16* bufA  = (u16*)p; p += (size_t)100352 * 512 * 2;   // yw / attn_out / h_ln2
    u16* bufB  = (u16*)p;                                   // qkv chunk / fc1 chunk

    const size_t fixed = ((size_t)786432 + 262144 + 1048576 + 1048576) * 2
                       + (size_t)262144 * 4 + (size_t)100352 * 512 * 2;
    const int nch = (ws_size >= fixed + (size_t)50176 * 2048 * 2) ? 2 : 4;
    const int chM = 100352 / nch;          // rows per chunk (multiple of 256 and 49)
    const int chWB = chM / 49;             // window-batches per chunk

    cvt_kernel<<<3072, 256, 0, stream>>>(qkvw, wq, 786432);
    cvt_kernel<<<1024, 256, 0, stream>>>(projw, wp, 262144);
    cvt_kernel<<<4096, 256, 0, stream>>>(fc1w, w1, 1048576);
    cvt_kernel<<<4096, 256, 0, stream>>>(fc2w, w2, 1048576);
    tbl_kernel<<<1024, 256, 0, stream>>>(relb, tbl);

    // LN1 + shift + window partition -> bufA (bf16, window layout)
    ln_kernel<true><<<25088, 256, 0, stream>>>(x, n1g, n1b, bufA);

    // QKV + attention, chunked
    for (int c = 0; c < nch; ++c) {
        const u16* Ach = bufA + (size_t)c * chM * 512;
        gemm5<0><<<(chM >> 8) * 6, 512, 0, stream>>>(Ach, wq, qkvb, chM, 1536, 512, bufB, nullptr);
        attn_kernel<<<chWB * 16, 256, 0, stream>>>(bufB, tbl, bufA, c * chWB);
    }

    // proj + window-reverse + unshift + residual -> d_out (x2, fp32)
    gemm5<2><<<392 * 2, 512, 0, stream>>>(bufA, wp, projb, 100352, 512, 512, out, x);

    // LN2 -> bufA (bf16)
    ln_kernel<false><<<25088, 256, 0, stream>>>(out, n2g, n2b, bufA);

    // MLP, chunked; fc2 accumulates into d_out
    for (int c = 0; c < nch; ++c) {
        const u16* Ach = bufA + (size_t)c * chM * 512;
        float* Och = out + (size_t)c * chM * 512;
        gemm5<1><<<(chM >> 8) * 8, 512, 0, stream>>>(Ach, w1, fc1b, chM, 2048, 512, bufB, nullptr);
        gemm5<3><<<(chM >> 8) * 2, 512, 0, stream>>>(bufB, w2, fc2b, chM, 512, 2048, Och, nullptr);
    }
}

// Round 7
// 1293.283 us; speedup vs baseline: 1.6881x; 1.0102x over previous
//
#include <hip/hip_runtime.h>

typedef unsigned short u16;
typedef unsigned int u32;
typedef __bf16 bf16x8 __attribute__((ext_vector_type(8)));
typedef float f32x4 __attribute__((ext_vector_type(4)));
typedef u16 u16x8 __attribute__((ext_vector_type(8)));

// ---------------- helpers ----------------
__device__ __forceinline__ u16 f2bf(float f) {
    union { float f; u32 u; } v; v.f = f;
    u32 r = v.u + 0x7fffu + ((v.u >> 16) & 1u);
    return (u16)(r >> 16);
}
__device__ __forceinline__ float gelu_f(float x) {
    // tanh-form GELU via sigmoid: gelu(x) = x * sigma(1.5957691*x + 0.0713548*x^3)
    float x2 = x * x;
    float z = x * fmaf(x2, 0.071354816f, 1.595769122f);
    return x * (1.0f / (1.0f + __expf(-z)));
}
__device__ __forceinline__ void async16(u16* lds, const u16* g) {
    __builtin_amdgcn_global_load_lds(
        (const __attribute__((address_space(1))) void*)g,
        (__attribute__((address_space(3))) void*)lds, 16, 0, 0);
}

// token index (window space) -> source/dest row in (B, 56, 56) raster order
__device__ __forceinline__ size_t win_to_img_row(int td) {
    int wb = td / 49, t = td - wb * 49;
    int bb = wb >> 6, w = wb & 63;
    int wh = w >> 3, ww = w & 7;
    int th = t / 7, tw = t - th * 7;
    int oh = wh * 7 + th + 3; if (oh >= 56) oh -= 56;
    int ow = ww * 7 + tw + 3; if (ow >= 56) ow -= 56;
    return ((size_t)bb * 3136 + oh * 56 + ow);
}

// ---------------- fp32 -> bf16 weight convert ----------------
__global__ void cvt_kernel(const float* __restrict__ s, u16* __restrict__ d, int n) {
    int i = blockIdx.x * 256 + threadIdx.x;
    if (i < n) d[i] = f2bf(s[i]);
}

// ---------------- bias+mask table: T[cat][head][64][64] fp32 ----------------
__global__ void tbl_kernel(const float* __restrict__ relb, float* __restrict__ T) {
    int i = blockIdx.x * 256 + threadIdx.x;      // 4*16*64*64 = 262144
    int c = i & 63, r = (i >> 6) & 63, head = (i >> 12) & 15, cat = i >> 16;
    float v;
    if (c >= 49 || r >= 49) v = -1e30f;
    else {
        int rh = r / 7, rw = r - rh * 7, ch = c / 7, cw = c - ch * 7;
        v = relb[((rh - ch + 6) * 13 + (rw - cw + 6)) * 16 + head];
        int lr = ((cat & 2) ? (rh < 4 ? 1 : 2) : 0) * 3 + ((cat & 1) ? (rw < 4 ? 1 : 2) : 0);
        int lc = ((cat & 2) ? (ch < 4 ? 1 : 2) : 0) * 3 + ((cat & 1) ? (cw < 4 ? 1 : 2) : 0);
        if (lr != lc) v -= 100.f;
    }
    T[i] = v;
}

// ---------------- LayerNorm (wave per token), optional shift+window gather ----------------
template <bool SHIFT>
__global__ __launch_bounds__(256) void ln_kernel(
    const float* __restrict__ src, const float* __restrict__ g,
    const float* __restrict__ b, u16* __restrict__ dst)
{
    const int lane = threadIdx.x & 63;
    const int td = blockIdx.x * 4 + (threadIdx.x >> 6);
    size_t so;
    if (SHIFT) so = win_to_img_row(td) * 512;
    else       so = (size_t)td * 512;

    const float4* px = (const float4*)(src + so);
    float4 v0 = px[lane * 2], v1 = px[lane * 2 + 1];
    float a[8] = {v0.x, v0.y, v0.z, v0.w, v1.x, v1.y, v1.z, v1.w};
    float s = 0.f, q = 0.f;
#pragma unroll
    for (int e = 0; e < 8; ++e) { s += a[e]; q += a[e] * a[e]; }
#pragma unroll
    for (int m = 32; m; m >>= 1) { s += __shfl_xor(s, m); q += __shfl_xor(q, m); }
    float mean = s * (1.f / 512.f);
    float var  = q * (1.f / 512.f) - mean * mean;
    float rstd = rsqrtf(var + 1e-5f);
    const int c0 = lane * 8;
    u16x8 o;
#pragma unroll
    for (int e = 0; e < 8; ++e)
        o[e] = f2bf((a[e] - mean) * rstd * g[c0 + e] + b[c0 + e]);
    *(u16x8*)(dst + (size_t)td * 512 + c0) = o;
}

// ---------------- 256x256 8-wave 8-phase bf16 GEMM (T2+T3+T4+T5) ----------------
// See R6 notes. R7: kh-outer MFMA order (dependency distance 8, was 1) + fast GELU.
// EPI: 0 = bf16 store, 1 = gelu+bf16, 2 = proj scatter+residual->fp32, 3 = fp32 +=
template <int EPI>
__global__ __launch_bounds__(512, 2) void gemm5(
    const u16* __restrict__ A, const u16* __restrict__ W,
    const float* __restrict__ bias, int M, int N, int K,
    void* __restrict__ Cout, const float* __restrict__ Xres)
{
    __shared__ __align__(16) u16 lds[65536];   // A: [2][256][64] @0, B: [2][256][64] @32768
    const int tid = threadIdx.x;
    const int lane = tid & 63, wv = tid >> 6;
    const int wr = wv >> 2, wc = wv & 3;
    const int ln = lane & 15, kq = lane >> 4;
    const int nbn = N >> 8;
    const int nwg = gridDim.x;
    const int wgid = ((nwg & 7) == 0) ? ((blockIdx.x & 7) * (nwg >> 3) + (blockIdx.x >> 3))
                                      : blockIdx.x;
    const int bm = wgid / nbn, bn = wgid - bm * nbn;
    const int m0 = bm << 8, n0 = bn << 8;

    // staging: 8 threads per 128B row; thread's 16B slot (tid&7) sources global
    // quantum (tid&7)^((row)&7) with row = tid>>3 within the 64-row unit
    const int sq = (((tid & 7) ^ ((tid >> 3) & 7)) << 3);
    const u16* gA = A + (size_t)(m0 + (tid >> 3)) * K + sq;
    const u16* gB = W + (size_t)(n0 + (tid >> 3)) * K + sq;

    // frag read bases (element idx); frag rows r have r&7 == ln&7
    const int baseA0 = (wr * 128 + ln) * 64 + (((kq) ^ (ln & 7)) << 3);
    const int baseA1 = (wr * 128 + ln) * 64 + (((4 + kq) ^ (ln & 7)) << 3);
    const int baseB0 = 32768 + (wc * 64 + ln) * 64 + (((kq) ^ (ln & 7)) << 3);
    const int baseB1 = 32768 + (wc * 64 + ln) * 64 + (((4 + kq) ^ (ln & 7)) << 3);

#define STA(dd, u, t) async16(lds + (dd) * 16384 + (u) * 4096 + tid * 8, \
                              gA + (size_t)(u) * 64 * K + (size_t)(t) * 64)
#define STB(dd, u, t) async16(lds + 32768 + (dd) * 16384 + (u) * 4096 + tid * 8, \
                              gB + (size_t)(u) * 64 * K + (size_t)(t) * 64)
#define LDA(dd, ms, kh) (*(const bf16x8*)(lds + (dd) * 16384 + ((kh) ? baseA1 : baseA0) + (ms) * 1024))
#define LDB(dd, ns, kh) (*(const bf16x8*)(lds + (dd) * 16384 + ((kh) ? baseB1 : baseB0) + (ns) * 1024))
#define BAR  __builtin_amdgcn_s_barrier()
#define LGKM do { asm volatile("s_waitcnt lgkmcnt(0)" ::: "memory"); \
                  __builtin_amdgcn_sched_barrier(0); } while (0)
// kh-outer MFMA cluster: 8 independent MFMAs per kh group (no 1-distance acc dependency)
#define MMQ(mb, nb) do { \
        __builtin_amdgcn_s_setprio(1); \
        _Pragma("unroll") \
        for (int kh = 0; kh < 2; ++kh) \
        _Pragma("unroll") \
        for (int ms = 0; ms < 4; ++ms) \
        _Pragma("unroll") \
        for (int nn = 0; nn < 2; ++nn) \
            acc[(mb) + ms][(nb) + nn] = __builtin_amdgcn_mfma_f32_16x16x32_bf16( \
                af[ms][kh], bf[nn][kh], acc[(mb) + ms][(nb) + nn], 0, 0, 0); \
        __builtin_amdgcn_s_setprio(0); \
    } while (0)

    const int nIter = K >> 7;                  // 2 K-tiles (BK=64) per iteration
    f32x4 acc[8][4] = {};
    bf16x8 af[4][2], bf[2][2];

    // ---- prologue: A(0), B(0), A(1) = 12 loads; oldest 8 must land ----
    STA(0, 0, 0); STA(0, 2, 0); STA(0, 1, 0); STA(0, 3, 0);
    STB(0, 0, 0); STB(0, 1, 0); STB(0, 2, 0); STB(0, 3, 0);
    STA(1, 0, 1); STA(1, 2, 1); STA(1, 1, 1); STA(1, 3, 1);
    asm volatile("s_waitcnt vmcnt(4)" ::: "memory");
    BAR;

    for (int it = 0; it < nIter; ++it) {
        const int T = 2 * it;
        const bool more = (it + 1 < nIter);
        // ---------------- P1: tile T (dbuf0) Q1 (m0-3, n0-1) ----------------
#pragma unroll
        for (int ms = 0; ms < 4; ++ms) { af[ms][0] = LDA(0, ms, 0); af[ms][1] = LDA(0, ms, 1); }
#pragma unroll
        for (int nn = 0; nn < 2; ++nn) { bf[nn][0] = LDB(0, nn, 0); bf[nn][1] = LDB(0, nn, 1); }
        STB(1, 0, T + 1); STB(1, 1, T + 1);
        BAR; LGKM;
        MMQ(0, 0);
        BAR;
        // ---------------- P2: Q2 (m0-3, n2-3) ----------------
#pragma unroll
        for (int nn = 0; nn < 2; ++nn) { bf[nn][0] = LDB(0, nn + 2, 0); bf[nn][1] = LDB(0, nn + 2, 1); }
        STB(1, 2, T + 1); STB(1, 3, T + 1);
        BAR; LGKM;
        MMQ(0, 2);
        BAR;
        // ---------------- P3: Q3 (m4-7, n2-3) ----------------
#pragma unroll
        for (int ms = 0; ms < 4; ++ms) { af[ms][0] = LDA(0, ms + 4, 0); af[ms][1] = LDA(0, ms + 4, 1); }
        if (more) { STA(0, 0, T + 2); STA(0, 2, T + 2); }
        BAR; LGKM;
        MMQ(4, 2);
        BAR;
        // ---------------- P4: Q4 (m4-7, n0-1) ----------------
#pragma unroll
        for (int nn = 0; nn < 2; ++nn) { bf[nn][0] = LDB(0, nn, 0); bf[nn][1] = LDB(0, nn, 1); }
        if (more) { STA(0, 1, T + 2); STA(0, 3, T + 2); }
        BAR; LGKM;
        MMQ(4, 0);
        if (more) asm volatile("s_waitcnt vmcnt(4)" ::: "memory");
        else      asm volatile("s_waitcnt vmcnt(0)" ::: "memory");
        BAR;
        // ---------------- P5: tile T+1 (dbuf1) Q1 ----------------
#pragma unroll
        for (int ms = 0; ms < 4; ++ms) { af[ms][0] = LDA(1, ms, 0); af[ms][1] = LDA(1, ms, 1); }
#pragma unroll
        for (int nn = 0; nn < 2; ++nn) { bf[nn][0] = LDB(1, nn, 0); bf[nn][1] = LDB(1, nn, 1); }
        if (more) { STB(0, 0, T + 2); STB(0, 1, T + 2); }
        BAR; LGKM;
        MMQ(0, 0);
        BAR;
        // ---------------- P6: Q2 ----------------
#pragma unroll
        for (int nn = 0; nn < 2; ++nn) { bf[nn][0] = LDB(1, nn + 2, 0); bf[nn][1] = LDB(1, nn + 2, 1); }
        if (more) { STB(0, 2, T + 2); STB(0, 3, T + 2); }
        BAR; LGKM;
        MMQ(0, 2);
        BAR;
        // ---------------- P7: Q3 ----------------
#pragma unroll
        for (int ms = 0; ms < 4; ++ms) { af[ms][0] = LDA(1, ms + 4, 0); af[ms][1] = LDA(1, ms + 4, 1); }
        if (more) { STA(1, 0, T + 3); STA(1, 2, T + 3); }
        BAR; LGKM;
        MMQ(4, 2);
        BAR;
        // ---------------- P8: Q4 ----------------
#pragma unroll
        for (int nn = 0; nn < 2; ++nn) { bf[nn][0] = LDB(1, nn, 0); bf[nn][1] = LDB(1, nn, 1); }
        if (more) { STA(1, 1, T + 3); STA(1, 3, T + 3); }
        BAR; LGKM;
        MMQ(4, 0);
        if (more) asm volatile("s_waitcnt vmcnt(4)" ::: "memory");
        BAR;
    }
#undef STA
#undef STB
#undef LDA
#undef LDB
#undef BAR
#undef LGKM
#undef MMQ

    // ---------- epilogue ----------
    float bs[4];
#pragma unroll
    for (int n = 0; n < 4; ++n) bs[n] = bias[n0 + wc * 64 + n * 16 + ln];
#pragma unroll
    for (int i = 0; i < 8; ++i) {
#pragma unroll
        for (int r = 0; r < 4; ++r) {
            const int row = m0 + wr * 128 + i * 16 + kq * 4 + r;
            size_t obase;
            if (EPI == 2) obase = win_to_img_row(row) * 512;
            else          obase = (size_t)row * N;
#pragma unroll
            for (int n = 0; n < 4; ++n) {
                const int col = n0 + wc * 64 + n * 16 + ln;
                float val = acc[i][n][r] + bs[n];
                if (EPI == 0) {
                    ((u16*)Cout)[obase + col] = f2bf(val);
                } else if (EPI == 1) {
                    ((u16*)Cout)[obase + col] = f2bf(gelu_f(val));
                } else if (EPI == 2) {
                    ((float*)Cout)[obase + col] = Xres[obase + col] + val;
                } else {
                    ((float*)Cout)[obase + col] += val;
                }
            }
        }
    }
}

// ---------------- MFMA windowed attention ----------------
__global__ __launch_bounds__(256) void attn_kernel(
    const u16* __restrict__ qkv, const float* __restrict__ tbl,
    u16* __restrict__ outp, int wbOff)
{
    __shared__ __align__(16) u16 qb[64][40];
    __shared__ __align__(16) u16 kb[64][40];
    __shared__ __align__(16) u16 vt[32][72];
    __shared__ __align__(16) u16 pb[64][72];

    const int tid = threadIdx.x;
    const int lane = tid & 63, wv = tid >> 6;
    const int wbl = blockIdx.x >> 4, head = blockIdx.x & 15;
    const int wbg = wbl + wbOff;
    const int w = wbg & 63;
    const int cat = (((w >> 3) == 7) ? 2 : 0) + (((w & 7) == 7) ? 1 : 0);
    const size_t base = (size_t)wbl * 49 * 1536 + head * 32;

    const u16x8 zz = {};
    for (int e = tid; e < 75; e += 256) {
        int r = 49 + e / 5, c8 = e % 5;
        *(u16x8*)&kb[r][c8 * 8] = zz;
    }
    for (int e = tid; e < 96; e += 256) {
        int d = e / 3, c8 = e % 3;
        *(u16x8*)&vt[d][48 + c8 * 8] = zz;
    }
    for (int e3 = tid; e3 < 588; e3 += 256) {
        int sel = e3 / 196, e = e3 - sel * 196;
        int r = e >> 2, c8 = e & 3;
        u16x8 v = *(const u16x8*)&qkv[base + (size_t)r * 1536 + sel * 512 + c8 * 8];
        if (sel == 0)      *(u16x8*)&qb[r][c8 * 8] = v;
        else if (sel == 1) *(u16x8*)&kb[r][c8 * 8] = v;
        else {
#pragma unroll
            for (int j = 0; j < 8; ++j) vt[c8 * 8 + j][r] = v[j];
        }
    }
    __syncthreads();

    const int ln = lane & 15, kq = lane >> 4;

    bf16x8 a = *(const bf16x8*)&qb[wv * 16 + ln][kq * 8];
    f32x4 acc[4] = {};
#pragma unroll
    for (int j = 0; j < 4; ++j) {
        bf16x8 b = *(const bf16x8*)&kb[j * 16 + ln][kq * 8];
        acc[j] = __builtin_amdgcn_mfma_f32_16x16x32_bf16(a, b, acc[j], 0, 0, 0);
    }

    const float* tb = tbl + (((cat * 16 + head) * 64) + wv * 16 + kq * 4) * 64 + ln;
    const float sc = 0.1767766952966369f;
    float inv[4];
#pragma unroll
    for (int t = 0; t < 4; ++t) {
        float v0 = acc[0][t] * sc + tb[t * 64];
        float v1 = acc[1][t] * sc + tb[t * 64 + 16];
        float v2 = acc[2][t] * sc + tb[t * 64 + 32];
        float v3 = acc[3][t] * sc + tb[t * 64 + 48];
        float m = fmaxf(fmaxf(v0, v1), fmaxf(v2, v3));
#pragma unroll
        for (int d = 1; d < 16; d <<= 1) m = fmaxf(m, __shfl_xor(m, d));
        v0 = __expf(v0 - m); v1 = __expf(v1 - m);
        v2 = __expf(v2 - m); v3 = __expf(v3 - m);
        float s = v0 + v1 + v2 + v3;
#pragma unroll
        for (int d = 1; d < 16; d <<= 1) s += __shfl_xor(s, d);
        inv[t] = 1.f / s;
        const int row = wv * 16 + kq * 4 + t;
        pb[row][ln]      = f2bf(v0);
        pb[row][ln + 16] = f2bf(v1);
        pb[row][ln + 32] = f2bf(v2);
        pb[row][ln + 48] = f2bf(v3);
    }

    f32x4 o[2] = {};
#pragma unroll
    for (int ks = 0; ks < 2; ++ks) {
        bf16x8 pa = *(const bf16x8*)&pb[wv * 16 + ln][ks * 32 + kq * 8];
#pragma unroll
        for (int j2 = 0; j2 < 2; ++j2) {
            bf16x8 vb = *(const bf16x8*)&vt[j2 * 16 + ln][ks * 32 + kq * 8];
            o[j2] = __builtin_amdgcn_mfma_f32_16x16x32_bf16(pa, vb, o[j2], 0, 0, 0);
        }
    }

#pragma unroll
    for (int t = 0; t < 4; ++t) {
        const int r = wv * 16 + kq * 4 + t;
        if (r < 49) {
            const size_t ob = ((size_t)(wbg * 49 + r)) * 512 + head * 32;
#pragma unroll
            for (int j2 = 0; j2 < 2; ++j2)
                outp[ob + j2 * 16 + ln] = f2bf(o[j2][t] * inv[t]);
        }
    }
}

// ---------------- launch ----------------
extern "C" void kernel_launch(void* const* d_in, const int* in_sizes, int n_in,
                              void* d_out, int out_size, void* d_ws, size_t ws_size,
                              hipStream_t stream)
{
    (void)in_sizes; (void)n_in; (void)out_size;
    const float* x     = (const float*)d_in[0];
    const float* n1g   = (const float*)d_in[1];
    const float* n1b   = (const float*)d_in[2];
    const float* qkvw  = (const float*)d_in[3];
    const float* qkvb  = (const float*)d_in[4];
    const float* relb  = (const float*)d_in[5];
    const float* projw = (const float*)d_in[6];
    const float* projb = (const float*)d_in[7];
    const float* n2g   = (const float*)d_in[8];
    const float* n2b   = (const float*)d_in[9];
    const float* fc1w  = (const float*)d_in[10];
    const float* fc1b  = (const float*)d_in[11];
    const float* fc2w  = (const float*)d_in[12];
    const float* fc2b  = (const float*)d_in[13];
    float* out = (float*)d_out;

    char* p = (char*)d_ws;
    u16* wq    = (u16*)p; p += (size_t)786432  * 2;
    u16* wp    = (u16*)p; p += (size_t)262144  * 2;
    u16* w1    = (u16*)p; p += (size_t)1048576 * 2;
    u16* w2    = (u16*)p; p += (size_t)1048576 * 2;
    float* tbl = (float*)p; p += (size_t)262144 * 4;
    u16* bufA  = (u16*)p; p += (size_t)100352 * 512 * 2;   // yw / attn_out / h_ln2
    u16* bufB  = (u16*)p;                                   // qkv chunk / fc1 chunk

    const size_t fixed = ((size_t)786432 + 262144 + 1048576 + 1048576) * 2
                       + (size_t)262144 * 4 + (size_t)100352 * 512 * 2;
    const int nch = (ws_size >= fixed + (size_t)50176 * 2048 * 2) ? 2 : 4;
    const int chM = 100352 / nch;          // rows per chunk (multiple of 256 and 49)
    const int chWB = chM / 49;             // window-batches per chunk

    cvt_kernel<<<3072, 256, 0, stream>>>(qkvw, wq, 786432);
    cvt_kernel<<<1024, 256, 0, stream>>>(projw, wp, 262144);
    cvt_kernel<<<4096, 256, 0, stream>>>(fc1w, w1, 1048576);
    cvt_kernel<<<4096, 256, 0, stream>>>(fc2w, w2, 1048576);
    tbl_kernel<<<1024, 256, 0, stream>>>(relb, tbl);

    // LN1 + shift + window partition -> bufA (bf16, window layout)
    ln_kernel<true><<<25088, 256, 0, stream>>>(x, n1g, n1b, bufA);

    // QKV + attention, chunked
    for (int c = 0; c < nch; ++c) {
        const u16* Ach = bufA + (size_t)c * chM * 512;
        gemm5<0><<<(chM >> 8) * 6, 512, 0, stream>>>(Ach, wq, qkvb, chM, 1536, 512, bufB, nullptr);
        attn_kernel<<<chWB * 16, 256, 0, stream>>>(bufB, tbl, bufA, c * chWB);
    }

    // proj + window-reverse + unshift + residual -> d_out (x2, fp32)
    gemm5<2><<<392 * 2, 512, 0, stream>>>(bufA, wp, projb, 100352, 512, 512, out, x);

    // LN2 -> bufA (bf16)
    ln_kernel<false><<<25088, 256, 0, stream>>>(out, n2g, n2b, bufA);

    // MLP, chunked; fc2 accumulates into d_out
    for (int c = 0; c < nch; ++c) {
        const u16* Ach = bufA + (size_t)c * chM * 512;
        float* Och = out + (size_t)c * chM * 512;
        gemm5<1><<<(chM >> 8) * 8, 512, 0, stream>>>(Ach, w1, fc1b, chM, 2048, 512, bufB, nullptr);
        gemm5<3><<<(chM >> 8) * 2, 512, 0, stream>>>(bufB, w2, fc2b, chM, 512, 2048, Och, nullptr);
    }
}

// Round 8
// 1254.352 us; speedup vs baseline: 1.7404x; 1.0310x over previous
//
#include <hip/hip_runtime.h>

typedef unsigned short u16;
typedef unsigned int u32;
typedef __bf16 bf16x8 __attribute__((ext_vector_type(8)));
typedef __bf16 bf16x2v __attribute__((ext_vector_type(2)));
typedef float f32x4 __attribute__((ext_vector_type(4)));
typedef u16 u16x8 __attribute__((ext_vector_type(8)));
typedef u32 u32x2 __attribute__((ext_vector_type(2)));

// ---------------- helpers ----------------
__device__ __forceinline__ u16 f2bf(float f) {
    union { float f; u32 u; } v; v.f = f;
    u32 r = v.u + 0x7fffu + ((v.u >> 16) & 1u);
    return (u16)(r >> 16);
}
// packed 2xf32 -> 2xbf16 in one u32 (compiler emits v_cvt_pk_bf16_f32)
__device__ __forceinline__ u32 pk2(float a, float b) {
    bf16x2v t; t[0] = (__bf16)a; t[1] = (__bf16)b;
    union { bf16x2v v; u32 u; } c; c.v = t; return c.u;
}
__device__ __forceinline__ float gelu_f(float x) {
    float x2 = x * x;
    float z = x * fmaf(x2, 0.071354816f, 1.595769122f);
    return x * (1.0f / (1.0f + __expf(-z)));
}
__device__ __forceinline__ void async16(u16* lds, const u16* g) {
    __builtin_amdgcn_global_load_lds(
        (const __attribute__((address_space(1))) void*)g,
        (__attribute__((address_space(3))) void*)lds, 16, 0, 0);
}

// token index (window space) -> source/dest row in (B, 56, 56) raster order
__device__ __forceinline__ size_t win_to_img_row(int td) {
    int wb = td / 49, t = td - wb * 49;
    int bb = wb >> 6, w = wb & 63;
    int wh = w >> 3, ww = w & 7;
    int th = t / 7, tw = t - th * 7;
    int oh = wh * 7 + th + 3; if (oh >= 56) oh -= 56;
    int ow = ww * 7 + tw + 3; if (ow >= 56) ow -= 56;
    return ((size_t)bb * 3136 + oh * 56 + ow);
}

// ---------------- fp32 -> bf16 weight convert ----------------
__global__ void cvt_kernel(const float* __restrict__ s, u16* __restrict__ d, int n) {
    int i = blockIdx.x * 256 + threadIdx.x;
    if (i < n) d[i] = f2bf(s[i]);
}
// fc2 weight convert with K-column permutation matching fc1's packed-store layout:
// pi64(k) = (k & ~63) | ((k&15)*4 + ((k>>4)&3))   (K = 2048)
__global__ void cvt_p64_kernel(const float* __restrict__ s, u16* __restrict__ d, int n) {
    int i = blockIdx.x * 256 + threadIdx.x;
    if (i < n) {
        int k = i & 2047, r = i >> 11;
        int pk_ = (k & ~63) | (((k & 15) << 2) | ((k >> 4) & 3));
        d[(r << 11) + pk_] = f2bf(s[i]);
    }
}

// ---------------- bias+mask table: T[cat][head][64][64] fp32 ----------------
__global__ void tbl_kernel(const float* __restrict__ relb, float* __restrict__ T) {
    int i = blockIdx.x * 256 + threadIdx.x;      // 4*16*64*64 = 262144
    int c = i & 63, r = (i >> 6) & 63, head = (i >> 12) & 15, cat = i >> 16;
    float v;
    if (c >= 49 || r >= 49) v = -1e30f;
    else {
        int rh = r / 7, rw = r - rh * 7, ch = c / 7, cw = c - ch * 7;
        v = relb[((rh - ch + 6) * 13 + (rw - cw + 6)) * 16 + head];
        int lr = ((cat & 2) ? (rh < 4 ? 1 : 2) : 0) * 3 + ((cat & 1) ? (rw < 4 ? 1 : 2) : 0);
        int lc = ((cat & 2) ? (ch < 4 ? 1 : 2) : 0) * 3 + ((cat & 1) ? (cw < 4 ? 1 : 2) : 0);
        if (lr != lc) v -= 100.f;
    }
    T[i] = v;
}

// ---------------- LayerNorm (wave per token), optional shift+window gather ----------------
template <bool SHIFT>
__global__ __launch_bounds__(256) void ln_kernel(
    const float* __restrict__ src, const float* __restrict__ g,
    const float* __restrict__ b, u16* __restrict__ dst)
{
    const int lane = threadIdx.x & 63;
    const int td = blockIdx.x * 4 + (threadIdx.x >> 6);
    size_t so;
    if (SHIFT) so = win_to_img_row(td) * 512;
    else       so = (size_t)td * 512;

    const float4* px = (const float4*)(src + so);
    float4 v0 = px[lane * 2], v1 = px[lane * 2 + 1];
    float a[8] = {v0.x, v0.y, v0.z, v0.w, v1.x, v1.y, v1.z, v1.w};
    float s = 0.f, q = 0.f;
#pragma unroll
    for (int e = 0; e < 8; ++e) { s += a[e]; q += a[e] * a[e]; }
#pragma unroll
    for (int m = 32; m; m >>= 1) { s += __shfl_xor(s, m); q += __shfl_xor(q, m); }
    float mean = s * (1.f / 512.f);
    float var  = q * (1.f / 512.f) - mean * mean;
    float rstd = rsqrtf(var + 1e-5f);
    const int c0 = lane * 8;
    u16x8 o;
#pragma unroll
    for (int e = 0; e < 8; ++e)
        o[e] = f2bf((a[e] - mean) * rstd * g[c0 + e] + b[c0 + e]);
    *(u16x8*)(dst + (size_t)td * 512 + c0) = o;
}

// ---------------- 256x256 8-wave 8-phase bf16 GEMM ----------------
// R8: B fragments for n0-1 AND n2-3 held in registers across the 4 quadrants
// (P4/P8 have no ds_reads); packed permuted epilogue stores for EPI 0/1.
// EPI0 output col permutation (within 32-col head blocks): slot = (d&15)*2 + (d>>4)
// EPI1 output col permutation (within 64-col blocks):      slot = (d&15)*4 + (d>>4)
// EPI: 0 = bf16 packed (qkv), 1 = gelu+bf16 packed (fc1),
//      2 = proj scatter+residual->fp32, 3 = fp32 += (fc2; W must be pi64-permuted)
template <int EPI>
__global__ __launch_bounds__(512, 2) void gemm6(
    const u16* __restrict__ A, const u16* __restrict__ W,
    const float* __restrict__ bias, int M, int N, int K,
    void* __restrict__ Cout, const float* __restrict__ Xres)
{
    __shared__ __align__(16) u16 lds[65536];   // A: [2][256][64] @0, B: [2][256][64] @32768
    const int tid = threadIdx.x;
    const int lane = tid & 63, wv = tid >> 6;
    const int wr = wv >> 2, wc = wv & 3;
    const int ln = lane & 15, kq = lane >> 4;
    const int nbn = N >> 8;
    const int nwg = gridDim.x;
    const int wgid = ((nwg & 7) == 0) ? ((blockIdx.x & 7) * (nwg >> 3) + (blockIdx.x >> 3))
                                      : blockIdx.x;
    const int bm = wgid / nbn, bn = wgid - bm * nbn;
    const int m0 = bm << 8, n0 = bn << 8;

    const int sq = (((tid & 7) ^ ((tid >> 3) & 7)) << 3);
    const u16* gA = A + (size_t)(m0 + (tid >> 3)) * K + sq;
    const u16* gB = W + (size_t)(n0 + (tid >> 3)) * K + sq;

    const int baseA0 = (wr * 128 + ln) * 64 + (((kq) ^ (ln & 7)) << 3);
    const int baseA1 = (wr * 128 + ln) * 64 + (((4 + kq) ^ (ln & 7)) << 3);
    const int baseB0 = 32768 + (wc * 64 + ln) * 64 + (((kq) ^ (ln & 7)) << 3);
    const int baseB1 = 32768 + (wc * 64 + ln) * 64 + (((4 + kq) ^ (ln & 7)) << 3);

#define STA(dd, u, t) async16(lds + (dd) * 16384 + (u) * 4096 + tid * 8, \
                              gA + (size_t)(u) * 64 * K + (size_t)(t) * 64)
#define STB(dd, u, t) async16(lds + 32768 + (dd) * 16384 + (u) * 4096 + tid * 8, \
                              gB + (size_t)(u) * 64 * K + (size_t)(t) * 64)
#define LDA(dd, ms, kh) (*(const bf16x8*)(lds + (dd) * 16384 + ((kh) ? baseA1 : baseA0) + (ms) * 1024))
#define LDB(dd, ns, kh) (*(const bf16x8*)(lds + (dd) * 16384 + ((kh) ? baseB1 : baseB0) + (ns) * 1024))
#define BAR  __builtin_amdgcn_s_barrier()
#define LGKM do { asm volatile("s_waitcnt lgkmcnt(0)" ::: "memory"); \
                  __builtin_amdgcn_sched_barrier(0); } while (0)
#define MMQ(mb, nb, BB) do { \
        __builtin_amdgcn_s_setprio(1); \
        _Pragma("unroll") \
        for (int kh = 0; kh < 2; ++kh) \
        _Pragma("unroll") \
        for (int ms = 0; ms < 4; ++ms) \
        _Pragma("unroll") \
        for (int nn = 0; nn < 2; ++nn) \
            acc[(mb) + ms][(nb) + nn] = __builtin_amdgcn_mfma_f32_16x16x32_bf16( \
                af[ms][kh], BB[nn][kh], acc[(mb) + ms][(nb) + nn], 0, 0, 0); \
        __builtin_amdgcn_s_setprio(0); \
    } while (0)

    const int nIter = K >> 7;
    f32x4 acc[8][4] = {};
    bf16x8 af[4][2], b01[2][2], b23[2][2];

    // ---- prologue: A(0), B(0), A(1) = 12 loads; oldest 8 must land ----
    STA(0, 0, 0); STA(0, 2, 0); STA(0, 1, 0); STA(0, 3, 0);
    STB(0, 0, 0); STB(0, 1, 0); STB(0, 2, 0); STB(0, 3, 0);
    STA(1, 0, 1); STA(1, 2, 1); STA(1, 1, 1); STA(1, 3, 1);
    asm volatile("s_waitcnt vmcnt(4)" ::: "memory");
    BAR;

    for (int it = 0; it < nIter; ++it) {
        const int T = 2 * it;
        const bool more = (it + 1 < nIter);
        // ---- P1: tile T (dbuf0) Q1 (m0-3, n0-1) ----
#pragma unroll
        for (int ms = 0; ms < 4; ++ms) { af[ms][0] = LDA(0, ms, 0); af[ms][1] = LDA(0, ms, 1); }
#pragma unroll
        for (int nn = 0; nn < 2; ++nn) { b01[nn][0] = LDB(0, nn, 0); b01[nn][1] = LDB(0, nn, 1); }
        STB(1, 0, T + 1); STB(1, 1, T + 1);
        BAR; LGKM;
        MMQ(0, 0, b01);
        BAR;
        // ---- P2: Q2 (m0-3, n2-3) ----
#pragma unroll
        for (int nn = 0; nn < 2; ++nn) { b23[nn][0] = LDB(0, nn + 2, 0); b23[nn][1] = LDB(0, nn + 2, 1); }
        STB(1, 2, T + 1); STB(1, 3, T + 1);
        BAR; LGKM;
        MMQ(0, 2, b23);
        BAR;
        // ---- P3: Q3 (m4-7, n2-3) ----
#pragma unroll
        for (int ms = 0; ms < 4; ++ms) { af[ms][0] = LDA(0, ms + 4, 0); af[ms][1] = LDA(0, ms + 4, 1); }
        if (more) { STA(0, 0, T + 2); STA(0, 2, T + 2); }
        BAR; LGKM;
        MMQ(4, 2, b23);
        BAR;
        // ---- P4: Q4 (m4-7, n0-1) -- no ds_reads ----
        if (more) { STA(0, 1, T + 2); STA(0, 3, T + 2); }
        BAR;
        MMQ(4, 0, b01);
        if (more) asm volatile("s_waitcnt vmcnt(4)" ::: "memory");
        else      asm volatile("s_waitcnt vmcnt(0)" ::: "memory");
        BAR;
        // ---- P5: tile T+1 (dbuf1) Q1 ----
#pragma unroll
        for (int ms = 0; ms < 4; ++ms) { af[ms][0] = LDA(1, ms, 0); af[ms][1] = LDA(1, ms, 1); }
#pragma unroll
        for (int nn = 0; nn < 2; ++nn) { b01[nn][0] = LDB(1, nn, 0); b01[nn][1] = LDB(1, nn, 1); }
        if (more) { STB(0, 0, T + 2); STB(0, 1, T + 2); }
        BAR; LGKM;
        MMQ(0, 0, b01);
        BAR;
        // ---- P6: Q2 ----
#pragma unroll
        for (int nn = 0; nn < 2; ++nn) { b23[nn][0] = LDB(1, nn + 2, 0); b23[nn][1] = LDB(1, nn + 2, 1); }
        if (more) { STB(0, 2, T + 2); STB(0, 3, T + 2); }
        BAR; LGKM;
        MMQ(0, 2, b23);
        BAR;
        // ---- P7: Q3 ----
#pragma unroll
        for (int ms = 0; ms < 4; ++ms) { af[ms][0] = LDA(1, ms + 4, 0); af[ms][1] = LDA(1, ms + 4, 1); }
        if (more) { STA(1, 0, T + 3); STA(1, 2, T + 3); }
        BAR; LGKM;
        MMQ(4, 2, b23);
        BAR;
        // ---- P8: Q4 -- no ds_reads ----
        if (more) { STA(1, 1, T + 3); STA(1, 3, T + 3); }
        BAR;
        MMQ(4, 0, b01);
        if (more) asm volatile("s_waitcnt vmcnt(4)" ::: "memory");
        BAR;
    }
#undef STA
#undef STB
#undef LDA
#undef LDB
#undef BAR
#undef LGKM
#undef MMQ

    // ---------- epilogue ----------
    float bs[4];
#pragma unroll
    for (int n = 0; n < 4; ++n) bs[n] = bias[n0 + wc * 64 + n * 16 + ln];
#pragma unroll
    for (int i = 0; i < 8; ++i) {
#pragma unroll
        for (int r = 0; r < 4; ++r) {
            const int row = m0 + wr * 128 + i * 16 + kq * 4 + r;
            if (EPI == 0) {
                u16* orow = (u16*)Cout + (size_t)row * N + n0 + wc * 64;
                float v0 = acc[i][0][r] + bs[0], v1 = acc[i][1][r] + bs[1];
                float v2 = acc[i][2][r] + bs[2], v3 = acc[i][3][r] + bs[3];
                *(u32*)(orow + ln * 2)      = pk2(v0, v1);
                *(u32*)(orow + 32 + ln * 2) = pk2(v2, v3);
            } else if (EPI == 1) {
                u16* orow = (u16*)Cout + (size_t)row * N + n0 + wc * 64;
                float v0 = gelu_f(acc[i][0][r] + bs[0]), v1 = gelu_f(acc[i][1][r] + bs[1]);
                float v2 = gelu_f(acc[i][2][r] + bs[2]), v3 = gelu_f(acc[i][3][r] + bs[3]);
                u32x2 pp = { pk2(v0, v1), pk2(v2, v3) };
                *(u32x2*)(orow + ln * 4) = pp;
            } else {
                size_t obase;
                if (EPI == 2) obase = win_to_img_row(row) * 512;
                else          obase = (size_t)row * N;
#pragma unroll
                for (int n = 0; n < 4; ++n) {
                    const int col = n0 + wc * 64 + n * 16 + ln;
                    float val = acc[i][n][r] + bs[n];
                    if (EPI == 2) ((float*)Cout)[obase + col] = Xres[obase + col] + val;
                    else          ((float*)Cout)[obase + col] += val;
                }
            }
        }
    }
}

// ---------------- MFMA windowed attention ----------------
// qkv input columns are permuted within each 32-col head block: slot = (d&15)*2 + (d>>4).
// Q.K^T is invariant (same permutation both sides); V is de-permuted during transpose staging.
__global__ __launch_bounds__(256) void attn_kernel(
    const u16* __restrict__ qkv, const float* __restrict__ tbl,
    u16* __restrict__ outp, int wbOff)
{
    __shared__ __align__(16) u16 qb[64][40];
    __shared__ __align__(16) u16 kb[64][40];
    __shared__ __align__(16) u16 vt[32][72];
    __shared__ __align__(16) u16 pb[64][72];

    const int tid = threadIdx.x;
    const int lane = tid & 63, wv = tid >> 6;
    const int wbl = blockIdx.x >> 4, head = blockIdx.x & 15;
    const int wbg = wbl + wbOff;
    const int w = wbg & 63;
    const int cat = (((w >> 3) == 7) ? 2 : 0) + (((w & 7) == 7) ? 1 : 0);
    const size_t base = (size_t)wbl * 49 * 1536 + head * 32;

    const u16x8 zz = {};
    for (int e = tid; e < 75; e += 256) {
        int r = 49 + e / 5, c8 = e % 5;
        *(u16x8*)&kb[r][c8 * 8] = zz;
    }
    for (int e = tid; e < 96; e += 256) {
        int d = e / 3, c8 = e % 3;
        *(u16x8*)&vt[d][48 + c8 * 8] = zz;
    }
    for (int e3 = tid; e3 < 588; e3 += 256) {
        int sel = e3 / 196, e = e3 - sel * 196;
        int r = e >> 2, c8 = e & 3;
        u16x8 v = *(const u16x8*)&qkv[base + (size_t)r * 1536 + sel * 512 + c8 * 8];
        if (sel == 0)      *(u16x8*)&qb[r][c8 * 8] = v;
        else if (sel == 1) *(u16x8*)&kb[r][c8 * 8] = v;
        else {
            // de-permute: slot s = c8*8+j holds original d = (s>>1) + 16*(s&1)
#pragma unroll
            for (int j = 0; j < 8; ++j) vt[c8 * 4 + (j >> 1) + ((j & 1) << 4)][r] = v[j];
        }
    }
    __syncthreads();

    const int ln = lane & 15, kq = lane >> 4;

    bf16x8 a = *(const bf16x8*)&qb[wv * 16 + ln][kq * 8];
    f32x4 acc[4] = {};
#pragma unroll
    for (int j = 0; j < 4; ++j) {
        bf16x8 b = *(const bf16x8*)&kb[j * 16 + ln][kq * 8];
        acc[j] = __builtin_amdgcn_mfma_f32_16x16x32_bf16(a, b, acc[j], 0, 0, 0);
    }

    const float* tb = tbl + (((cat * 16 + head) * 64) + wv * 16 + kq * 4) * 64 + ln;
    const float sc = 0.1767766952966369f;
    float inv[4];
#pragma unroll
    for (int t = 0; t < 4; ++t) {
        float v0 = acc[0][t] * sc + tb[t * 64];
        float v1 = acc[1][t] * sc + tb[t * 64 + 16];
        float v2 = acc[2][t] * sc + tb[t * 64 + 32];
        float v3 = acc[3][t] * sc + tb[t * 64 + 48];
        float m = fmaxf(fmaxf(v0, v1), fmaxf(v2, v3));
#pragma unroll
        for (int d = 1; d < 16; d <<= 1) m = fmaxf(m, __shfl_xor(m, d));
        v0 = __expf(v0 - m); v1 = __expf(v1 - m);
        v2 = __expf(v2 - m); v3 = __expf(v3 - m);
        float s = v0 + v1 + v2 + v3;
#pragma unroll
        for (int d = 1; d < 16; d <<= 1) s += __shfl_xor(s, d);
        inv[t] = 1.f / s;
        const int row = wv * 16 + kq * 4 + t;
        pb[row][ln]      = f2bf(v0);
        pb[row][ln + 16] = f2bf(v1);
        pb[row][ln + 32] = f2bf(v2);
        pb[row][ln + 48] = f2bf(v3);
    }

    f32x4 o[2] = {};
#pragma unroll
    for (int ks = 0; ks < 2; ++ks) {
        bf16x8 pa = *(const bf16x8*)&pb[wv * 16 + ln][ks * 32 + kq * 8];
#pragma unroll
        for (int j2 = 0; j2 < 2; ++j2) {
            bf16x8 vb = *(const bf16x8*)&vt[j2 * 16 + ln][ks * 32 + kq * 8];
            o[j2] = __builtin_amdgcn_mfma_f32_16x16x32_bf16(pa, vb, o[j2], 0, 0, 0);
        }
    }

#pragma unroll
    for (int t = 0; t < 4; ++t) {
        const int r = wv * 16 + kq * 4 + t;
        if (r < 49) {
            const size_t ob = ((size_t)(wbg * 49 + r)) * 512 + head * 32;
#pragma unroll
            for (int j2 = 0; j2 < 2; ++j2)
                outp[ob + j2 * 16 + ln] = f2bf(o[j2][t] * inv[t]);
        }
    }
}

// ---------------- launch ----------------
extern "C" void kernel_launch(void* const* d_in, const int* in_sizes, int n_in,
                              void* d_out, int out_size, void* d_ws, size_t ws_size,
                              hipStream_t stream)
{
    (void)in_sizes; (void)n_in; (void)out_size;
    const float* x     = (const float*)d_in[0];
    const float* n1g   = (const float*)d_in[1];
    const float* n1b   = (const float*)d_in[2];
    const float* qkvw  = (const float*)d_in[3];
    const float* qkvb  = (const float*)d_in[4];
    const float* relb  = (const float*)d_in[5];
    const float* projw = (const float*)d_in[6];
    const float* projb = (const float*)d_in[7];
    const float* n2g   = (const float*)d_in[8];
    const float* n2b   = (const float*)d_in[9];
    const float* fc1w  = (const float*)d_in[10];
    const float* fc1b  = (const float*)d_in[11];
    const float* fc2w  = (const float*)d_in[12];
    const float* fc2b  = (const float*)d_in[13];
    float* out = (float*)d_out;

    char* p = (char*)d_ws;
    u16* wq    = (u16*)p; p += (size_t)786432  * 2;
    u16* wp    = (u16*)p; p += (size_t)262144  * 2;
    u16* w1    = (u16*)p; p += (size_t)1048576 * 2;
    u16* w2    = (u16*)p; p += (size_t)1048576 * 2;
    float* tbl = (float*)p; p += (size_t)262144 * 4;
    u16* bufA  = (u16*)p; p += (size_t)100352 * 512 * 2;   // yw / attn_out / h_ln2
    u16* bufB  = (u16*)p;                                   // qkv chunk / fc1 chunk

    const size_t fixed = ((size_t)786432 + 262144 + 1048576 + 1048576) * 2
                       + (size_t)262144 * 4 + (size_t)100352 * 512 * 2;
    const int nch = (ws_size >= fixed + (size_t)50176 * 2048 * 2) ? 2 : 4;
    const int chM = 100352 / nch;          // rows per chunk (multiple of 256 and 49)
    const int chWB = chM / 49;             // window-batches per chunk

    cvt_kernel<<<3072, 256, 0, stream>>>(qkvw, wq, 786432);
    cvt_kernel<<<1024, 256, 0, stream>>>(projw, wp, 262144);
    cvt_kernel<<<4096, 256, 0, stream>>>(fc1w, w1, 1048576);
    cvt_p64_kernel<<<4096, 256, 0, stream>>>(fc2w, w2, 1048576);
    tbl_kernel<<<1024, 256, 0, stream>>>(relb, tbl);

    // LN1 + shift + window partition -> bufA (bf16, window layout)
    ln_kernel<true><<<25088, 256, 0, stream>>>(x, n1g, n1b, bufA);

    // QKV + attention, chunked
    for (int c = 0; c < nch; ++c) {
        const u16* Ach = bufA + (size_t)c * chM * 512;
        gemm6<0><<<(chM >> 8) * 6, 512, 0, stream>>>(Ach, wq, qkvb, chM, 1536, 512, bufB, nullptr);
        attn_kernel<<<chWB * 16, 256, 0, stream>>>(bufB, tbl, bufA, c * chWB);
    }

    // proj + window-reverse + unshift + residual -> d_out (x2, fp32)
    gemm6<2><<<392 * 2, 512, 0, stream>>>(bufA, wp, projb, 100352, 512, 512, out, x);

    // LN2 -> bufA (bf16)
    ln_kernel<false><<<25088, 256, 0, stream>>>(out, n2g, n2b, bufA);

    // MLP, chunked; fc2 accumulates into d_out
    for (int c = 0; c < nch; ++c) {
        const u16* Ach = bufA + (size_t)c * chM * 512;
        float* Och = out + (size_t)c * chM * 512;
        gemm6<1><<<(chM >> 8) * 8, 512, 0, stream>>>(Ach, w1, fc1b, chM, 2048, 512, bufB, nullptr);
        gemm6<3><<<(chM >> 8) * 2, 512, 0, stream>>>(bufB, w2, fc2b, chM, 512, 2048, Och, nullptr);
    }
}

// Round 9
// 1247.744 us; speedup vs baseline: 1.7497x; 1.0053x over previous
//
#include <hip/hip_runtime.h>

typedef unsigned short u16;
typedef unsigned int u32;
typedef __bf16 bf16x8 __attribute__((ext_vector_type(8)));
typedef __bf16 bf16x2v __attribute__((ext_vector_type(2)));
typedef float f32x4 __attribute__((ext_vector_type(4)));
typedef u16 u16x8 __attribute__((ext_vector_type(8)));
typedef u32 u32x2 __attribute__((ext_vector_type(2)));

// ---------------- helpers ----------------
__device__ __forceinline__ u16 f2bf(float f) {
    union { float f; u32 u; } v; v.f = f;
    u32 r = v.u + 0x7fffu + ((v.u >> 16) & 1u);
    return (u16)(r >> 16);
}
// packed 2xf32 -> 2xbf16 in one u32 (compiler emits v_cvt_pk_bf16_f32)
__device__ __forceinline__ u32 pk2(float a, float b) {
    bf16x2v t; t[0] = (__bf16)a; t[1] = (__bf16)b;
    union { bf16x2v v; u32 u; } c; c.v = t; return c.u;
}
__device__ __forceinline__ float gelu_f(float x) {
    float x2 = x * x;
    float z = x * fmaf(x2, 0.071354816f, 1.595769122f);
    return x * (1.0f / (1.0f + __expf(-z)));
}
__device__ __forceinline__ void async16(u16* lds, const u16* g) {
    __builtin_amdgcn_global_load_lds(
        (const __attribute__((address_space(1))) void*)g,
        (__attribute__((address_space(3))) void*)lds, 16, 0, 0);
}

// token index (window space) -> source/dest row in (B, 56, 56) raster order
__device__ __forceinline__ size_t win_to_img_row(int td) {
    int wb = td / 49, t = td - wb * 49;
    int bb = wb >> 6, w = wb & 63;
    int wh = w >> 3, ww = w & 7;
    int th = t / 7, tw = t - th * 7;
    int oh = wh * 7 + th + 3; if (oh >= 56) oh -= 56;
    int ow = ww * 7 + tw + 3; if (ow >= 56) ow -= 56;
    return ((size_t)bb * 3136 + oh * 56 + ow);
}

// ---------------- fp32 -> bf16 weight convert ----------------
__global__ void cvt_kernel(const float* __restrict__ s, u16* __restrict__ d, int n) {
    int i = blockIdx.x * 256 + threadIdx.x;
    if (i < n) d[i] = f2bf(s[i]);
}
// fc2 weight convert with K-column permutation matching fc1's packed-store layout:
// pi64(k) = (k & ~63) | ((k&15)*4 + ((k>>4)&3))   (K = 2048)
__global__ void cvt_p64_kernel(const float* __restrict__ s, u16* __restrict__ d, int n) {
    int i = blockIdx.x * 256 + threadIdx.x;
    if (i < n) {
        int k = i & 2047, r = i >> 11;
        int pk_ = (k & ~63) | (((k & 15) << 2) | ((k >> 4) & 3));
        d[(r << 11) + pk_] = f2bf(s[i]);
    }
}

// ---------------- bias+mask table: T[cat][head][64][64] fp32 ----------------
__global__ void tbl_kernel(const float* __restrict__ relb, float* __restrict__ T) {
    int i = blockIdx.x * 256 + threadIdx.x;      // 4*16*64*64 = 262144
    int c = i & 63, r = (i >> 6) & 63, head = (i >> 12) & 15, cat = i >> 16;
    float v;
    if (c >= 49 || r >= 49) v = -1e30f;
    else {
        int rh = r / 7, rw = r - rh * 7, ch = c / 7, cw = c - ch * 7;
        v = relb[((rh - ch + 6) * 13 + (rw - cw + 6)) * 16 + head];
        int lr = ((cat & 2) ? (rh < 4 ? 1 : 2) : 0) * 3 + ((cat & 1) ? (rw < 4 ? 1 : 2) : 0);
        int lc = ((cat & 2) ? (ch < 4 ? 1 : 2) : 0) * 3 + ((cat & 1) ? (cw < 4 ? 1 : 2) : 0);
        if (lr != lc) v -= 100.f;
    }
    T[i] = v;
}

// ---------------- LayerNorm (wave per token), optional shift+window gather ----------------
template <bool SHIFT>
__global__ __launch_bounds__(256) void ln_kernel(
    const float* __restrict__ src, const float* __restrict__ g,
    const float* __restrict__ b, u16* __restrict__ dst)
{
    const int lane = threadIdx.x & 63;
    const int td = blockIdx.x * 4 + (threadIdx.x >> 6);
    size_t so;
    if (SHIFT) so = win_to_img_row(td) * 512;
    else       so = (size_t)td * 512;

    const float4* px = (const float4*)(src + so);
    float4 v0 = px[lane * 2], v1 = px[lane * 2 + 1];
    float a[8] = {v0.x, v0.y, v0.z, v0.w, v1.x, v1.y, v1.z, v1.w};
    float s = 0.f, q = 0.f;
#pragma unroll
    for (int e = 0; e < 8; ++e) { s += a[e]; q += a[e] * a[e]; }
#pragma unroll
    for (int m = 32; m; m >>= 1) { s += __shfl_xor(s, m); q += __shfl_xor(q, m); }
    float mean = s * (1.f / 512.f);
    float var  = q * (1.f / 512.f) - mean * mean;
    float rstd = rsqrtf(var + 1e-5f);
    const int c0 = lane * 8;
    u16x8 o;
#pragma unroll
    for (int e = 0; e < 8; ++e)
        o[e] = f2bf((a[e] - mean) * rstd * g[c0 + e] + b[c0 + e]);
    *(u16x8*)(dst + (size_t)td * 512 + c0) = o;
}

// ---------------- 256x256 8-wave 8-phase bf16 GEMM ----------------
// R9: removed per-phase sched_barrier(0) + explicit lgkmcnt(0) (m141 anti-pattern;
// compiler inserts fine-grained lgkmcnt for plain-C++ ds_reads) and dropped to ONE
// barrier per phase. Phase = {C++ ds_reads | stage issues | setprio1 MFMA setprio0 |
// [counted vmcnt P4/P8] | s_barrier}. Buffer-hazard audit: every stage-write targets
// a region whose last readers are >=2 phases back; 1 bar/phase bounds skew <1 phase.
// EPI: 0 = bf16 packed (qkv), 1 = gelu+bf16 packed (fc1),
//      2 = proj scatter+residual->fp32, 3 = fp32 += (fc2; W must be pi64-permuted)
template <int EPI>
__global__ __launch_bounds__(512, 2) void gemm6(
    const u16* __restrict__ A, const u16* __restrict__ W,
    const float* __restrict__ bias, int M, int N, int K,
    void* __restrict__ Cout, const float* __restrict__ Xres)
{
    __shared__ __align__(16) u16 lds[65536];   // A: [2][256][64] @0, B: [2][256][64] @32768
    const int tid = threadIdx.x;
    const int lane = tid & 63, wv = tid >> 6;
    const int wr = wv >> 2, wc = wv & 3;
    const int ln = lane & 15, kq = lane >> 4;
    const int nbn = N >> 8;
    const int nwg = gridDim.x;
    const int wgid = ((nwg & 7) == 0) ? ((blockIdx.x & 7) * (nwg >> 3) + (blockIdx.x >> 3))
                                      : blockIdx.x;
    const int bm = wgid / nbn, bn = wgid - bm * nbn;
    const int m0 = bm << 8, n0 = bn << 8;

    const int sq = (((tid & 7) ^ ((tid >> 3) & 7)) << 3);
    const u16* gA = A + (size_t)(m0 + (tid >> 3)) * K + sq;
    const u16* gB = W + (size_t)(n0 + (tid >> 3)) * K + sq;

    const int baseA0 = (wr * 128 + ln) * 64 + (((kq) ^ (ln & 7)) << 3);
    const int baseA1 = (wr * 128 + ln) * 64 + (((4 + kq) ^ (ln & 7)) << 3);
    const int baseB0 = 32768 + (wc * 64 + ln) * 64 + (((kq) ^ (ln & 7)) << 3);
    const int baseB1 = 32768 + (wc * 64 + ln) * 64 + (((4 + kq) ^ (ln & 7)) << 3);

#define STA(dd, u, t) async16(lds + (dd) * 16384 + (u) * 4096 + tid * 8, \
                              gA + (size_t)(u) * 64 * K + (size_t)(t) * 64)
#define STB(dd, u, t) async16(lds + 32768 + (dd) * 16384 + (u) * 4096 + tid * 8, \
                              gB + (size_t)(u) * 64 * K + (size_t)(t) * 64)
#define LDA(dd, ms, kh) (*(const bf16x8*)(lds + (dd) * 16384 + ((kh) ? baseA1 : baseA0) + (ms) * 1024))
#define LDB(dd, ns, kh) (*(const bf16x8*)(lds + (dd) * 16384 + ((kh) ? baseB1 : baseB0) + (ns) * 1024))
#define BAR  __builtin_amdgcn_s_barrier()
#define MMQ(mb, nb, BB) do { \
        __builtin_amdgcn_s_setprio(1); \
        _Pragma("unroll") \
        for (int kh = 0; kh < 2; ++kh) \
        _Pragma("unroll") \
        for (int ms = 0; ms < 4; ++ms) \
        _Pragma("unroll") \
        for (int nn = 0; nn < 2; ++nn) \
            acc[(mb) + ms][(nb) + nn] = __builtin_amdgcn_mfma_f32_16x16x32_bf16( \
                af[ms][kh], BB[nn][kh], acc[(mb) + ms][(nb) + nn], 0, 0, 0); \
        __builtin_amdgcn_s_setprio(0); \
    } while (0)

    const int nIter = K >> 7;
    f32x4 acc[8][4] = {};
    bf16x8 af[4][2], b01[2][2], b23[2][2];

    // ---- prologue: A(0), B(0), A(1) = 12 loads; oldest 8 must land ----
    STA(0, 0, 0); STA(0, 2, 0); STA(0, 1, 0); STA(0, 3, 0);
    STB(0, 0, 0); STB(0, 1, 0); STB(0, 2, 0); STB(0, 3, 0);
    STA(1, 0, 1); STA(1, 2, 1); STA(1, 1, 1); STA(1, 3, 1);
    asm volatile("s_waitcnt vmcnt(4)" ::: "memory");
    BAR;

    for (int it = 0; it < nIter; ++it) {
        const int T = 2 * it;
        const bool more = (it + 1 < nIter);
        // ---- P1: tile T (dbuf0) Q1 (m0-3, n0-1) ----
#pragma unroll
        for (int ms = 0; ms < 4; ++ms) { af[ms][0] = LDA(0, ms, 0); af[ms][1] = LDA(0, ms, 1); }
#pragma unroll
        for (int nn = 0; nn < 2; ++nn) { b01[nn][0] = LDB(0, nn, 0); b01[nn][1] = LDB(0, nn, 1); }
        STB(1, 0, T + 1); STB(1, 1, T + 1);
        MMQ(0, 0, b01);
        BAR;
        // ---- P2: Q2 (m0-3, n2-3) ----
#pragma unroll
        for (int nn = 0; nn < 2; ++nn) { b23[nn][0] = LDB(0, nn + 2, 0); b23[nn][1] = LDB(0, nn + 2, 1); }
        STB(1, 2, T + 1); STB(1, 3, T + 1);
        MMQ(0, 2, b23);
        BAR;
        // ---- P3: Q3 (m4-7, n2-3) ----
#pragma unroll
        for (int ms = 0; ms < 4; ++ms) { af[ms][0] = LDA(0, ms + 4, 0); af[ms][1] = LDA(0, ms + 4, 1); }
        if (more) { STA(0, 0, T + 2); STA(0, 2, T + 2); }
        MMQ(4, 2, b23);
        BAR;
        // ---- P4: Q4 (m4-7, n0-1) -- no ds_reads ----
        if (more) { STA(0, 1, T + 2); STA(0, 3, T + 2); }
        MMQ(4, 0, b01);
        if (more) asm volatile("s_waitcnt vmcnt(4)" ::: "memory");
        else      asm volatile("s_waitcnt vmcnt(0)" ::: "memory");
        BAR;
        // ---- P5: tile T+1 (dbuf1) Q1 ----
#pragma unroll
        for (int ms = 0; ms < 4; ++ms) { af[ms][0] = LDA(1, ms, 0); af[ms][1] = LDA(1, ms, 1); }
#pragma unroll
        for (int nn = 0; nn < 2; ++nn) { b01[nn][0] = LDB(1, nn, 0); b01[nn][1] = LDB(1, nn, 1); }
        if (more) { STB(0, 0, T + 2); STB(0, 1, T + 2); }
        MMQ(0, 0, b01);
        BAR;
        // ---- P6: Q2 ----
#pragma unroll
        for (int nn = 0; nn < 2; ++nn) { b23[nn][0] = LDB(1, nn + 2, 0); b23[nn][1] = LDB(1, nn + 2, 1); }
        if (more) { STB(0, 2, T + 2); STB(0, 3, T + 2); }
        MMQ(0, 2, b23);
        BAR;
        // ---- P7: Q3 ----
#pragma unroll
        for (int ms = 0; ms < 4; ++ms) { af[ms][0] = LDA(1, ms + 4, 0); af[ms][1] = LDA(1, ms + 4, 1); }
        if (more) { STA(1, 0, T + 3); STA(1, 2, T + 3); }
        MMQ(4, 2, b23);
        BAR;
        // ---- P8: Q4 -- no ds_reads ----
        if (more) { STA(1, 1, T + 3); STA(1, 3, T + 3); }
        MMQ(4, 0, b01);
        if (more) asm volatile("s_waitcnt vmcnt(4)" ::: "memory");
        BAR;
    }
#undef STA
#undef STB
#undef LDA
#undef LDB
#undef BAR
#undef MMQ

    // ---------- epilogue ----------
    float bs[4];
#pragma unroll
    for (int n = 0; n < 4; ++n) bs[n] = bias[n0 + wc * 64 + n * 16 + ln];
#pragma unroll
    for (int i = 0; i < 8; ++i) {
#pragma unroll
        for (int r = 0; r < 4; ++r) {
            const int row = m0 + wr * 128 + i * 16 + kq * 4 + r;
            if (EPI == 0) {
                u16* orow = (u16*)Cout + (size_t)row * N + n0 + wc * 64;
                float v0 = acc[i][0][r] + bs[0], v1 = acc[i][1][r] + bs[1];
                float v2 = acc[i][2][r] + bs[2], v3 = acc[i][3][r] + bs[3];
                *(u32*)(orow + ln * 2)      = pk2(v0, v1);
                *(u32*)(orow + 32 + ln * 2) = pk2(v2, v3);
            } else if (EPI == 1) {
                u16* orow = (u16*)Cout + (size_t)row * N + n0 + wc * 64;
                float v0 = gelu_f(acc[i][0][r] + bs[0]), v1 = gelu_f(acc[i][1][r] + bs[1]);
                float v2 = gelu_f(acc[i][2][r] + bs[2]), v3 = gelu_f(acc[i][3][r] + bs[3]);
                u32x2 pp = { pk2(v0, v1), pk2(v2, v3) };
                *(u32x2*)(orow + ln * 4) = pp;
            } else {
                size_t obase;
                if (EPI == 2) obase = win_to_img_row(row) * 512;
                else          obase = (size_t)row * N;
#pragma unroll
                for (int n = 0; n < 4; ++n) {
                    const int col = n0 + wc * 64 + n * 16 + ln;
                    float val = acc[i][n][r] + bs[n];
                    if (EPI == 2) ((float*)Cout)[obase + col] = Xres[obase + col] + val;
                    else          ((float*)Cout)[obase + col] += val;
                }
            }
        }
    }
}

// ---------------- MFMA windowed attention ----------------
// qkv input columns are permuted within each 32-col head block: slot = (d&15)*2 + (d>>4).
// Q.K^T is invariant (same permutation both sides); V is de-permuted during transpose staging.
__global__ __launch_bounds__(256) void attn_kernel(
    const u16* __restrict__ qkv, const float* __restrict__ tbl,
    u16* __restrict__ outp, int wbOff)
{
    __shared__ __align__(16) u16 qb[64][40];
    __shared__ __align__(16) u16 kb[64][40];
    __shared__ __align__(16) u16 vt[32][72];
    __shared__ __align__(16) u16 pb[64][72];

    const int tid = threadIdx.x;
    const int lane = tid & 63, wv = tid >> 6;
    const int wbl = blockIdx.x >> 4, head = blockIdx.x & 15;
    const int wbg = wbl + wbOff;
    const int w = wbg & 63;
    const int cat = (((w >> 3) == 7) ? 2 : 0) + (((w & 7) == 7) ? 1 : 0);
    const size_t base = (size_t)wbl * 49 * 1536 + head * 32;

    const u16x8 zz = {};
    for (int e = tid; e < 75; e += 256) {
        int r = 49 + e / 5, c8 = e % 5;
        *(u16x8*)&kb[r][c8 * 8] = zz;
    }
    for (int e = tid; e < 96; e += 256) {
        int d = e / 3, c8 = e % 3;
        *(u16x8*)&vt[d][48 + c8 * 8] = zz;
    }
    for (int e3 = tid; e3 < 588; e3 += 256) {
        int sel = e3 / 196, e = e3 - sel * 196;
        int r = e >> 2, c8 = e & 3;
        u16x8 v = *(const u16x8*)&qkv[base + (size_t)r * 1536 + sel * 512 + c8 * 8];
        if (sel == 0)      *(u16x8*)&qb[r][c8 * 8] = v;
        else if (sel == 1) *(u16x8*)&kb[r][c8 * 8] = v;
        else {
            // de-permute: slot s = c8*8+j holds original d = (s>>1) + 16*(s&1)
#pragma unroll
            for (int j = 0; j < 8; ++j) vt[c8 * 4 + (j >> 1) + ((j & 1) << 4)][r] = v[j];
        }
    }
    __syncthreads();

    const int ln = lane & 15, kq = lane >> 4;

    bf16x8 a = *(const bf16x8*)&qb[wv * 16 + ln][kq * 8];
    f32x4 acc[4] = {};
#pragma unroll
    for (int j = 0; j < 4; ++j) {
        bf16x8 b = *(const bf16x8*)&kb[j * 16 + ln][kq * 8];
        acc[j] = __builtin_amdgcn_mfma_f32_16x16x32_bf16(a, b, acc[j], 0, 0, 0);
    }

    const float* tb = tbl + (((cat * 16 + head) * 64) + wv * 16 + kq * 4) * 64 + ln;
    const float sc = 0.1767766952966369f;
    float inv[4];
#pragma unroll
    for (int t = 0; t < 4; ++t) {
        float v0 = acc[0][t] * sc + tb[t * 64];
        float v1 = acc[1][t] * sc + tb[t * 64 + 16];
        float v2 = acc[2][t] * sc + tb[t * 64 + 32];
        float v3 = acc[3][t] * sc + tb[t * 64 + 48];
        float m = fmaxf(fmaxf(v0, v1), fmaxf(v2, v3));
#pragma unroll
        for (int d = 1; d < 16; d <<= 1) m = fmaxf(m, __shfl_xor(m, d));
        v0 = __expf(v0 - m); v1 = __expf(v1 - m);
        v2 = __expf(v2 - m); v3 = __expf(v3 - m);
        float s = v0 + v1 + v2 + v3;
#pragma unroll
        for (int d = 1; d < 16; d <<= 1) s += __shfl_xor(s, d);
        inv[t] = 1.f / s;
        const int row = wv * 16 + kq * 4 + t;
        pb[row][ln]      = f2bf(v0);
        pb[row][ln + 16] = f2bf(v1);
        pb[row][ln + 32] = f2bf(v2);
        pb[row][ln + 48] = f2bf(v3);
    }

    f32x4 o[2] = {};
#pragma unroll
    for (int ks = 0; ks < 2; ++ks) {
        bf16x8 pa = *(const bf16x8*)&pb[wv * 16 + ln][ks * 32 + kq * 8];
#pragma unroll
        for (int j2 = 0; j2 < 2; ++j2) {
            bf16x8 vb = *(const bf16x8*)&vt[j2 * 16 + ln][ks * 32 + kq * 8];
            o[j2] = __builtin_amdgcn_mfma_f32_16x16x32_bf16(pa, vb, o[j2], 0, 0, 0);
        }
    }

#pragma unroll
    for (int t = 0; t < 4; ++t) {
        const int r = wv * 16 + kq * 4 + t;
        if (r < 49) {
            const size_t ob = ((size_t)(wbg * 49 + r)) * 512 + head * 32;
#pragma unroll
            for (int j2 = 0; j2 < 2; ++j2)
                outp[ob + j2 * 16 + ln] = f2bf(o[j2][t] * inv[t]);
        }
    }
}

// ---------------- launch ----------------
extern "C" void kernel_launch(void* const* d_in, const int* in_sizes, int n_in,
                              void* d_out, int out_size, void* d_ws, size_t ws_size,
                              hipStream_t stream)
{
    (void)in_sizes; (void)n_in; (void)out_size;
    const float* x     = (const float*)d_in[0];
    const float* n1g   = (const float*)d_in[1];
    const float* n1b   = (const float*)d_in[2];
    const float* qkvw  = (const float*)d_in[3];
    const float* qkvb  = (const float*)d_in[4];
    const float* relb  = (const float*)d_in[5];
    const float* projw = (const float*)d_in[6];
    const float* projb = (const float*)d_in[7];
    const float* n2g   = (const float*)d_in[8];
    const float* n2b   = (const float*)d_in[9];
    const float* fc1w  = (const float*)d_in[10];
    const float* fc1b  = (const float*)d_in[11];
    const float* fc2w  = (const float*)d_in[12];
    const float* fc2b  = (const float*)d_in[13];
    float* out = (float*)d_out;

    char* p = (char*)d_ws;
    u16* wq    = (u16*)p; p += (size_t)786432  * 2;
    u16* wp    = (u16*)p; p += (size_t)262144  * 2;
    u16* w1    = (u16*)p; p += (size_t)1048576 * 2;
    u16* w2    = (u16*)p; p += (size_t)1048576 * 2;
    float* tbl = (float*)p; p += (size_t)262144 * 4;
    u16* bufA  = (u16*)p; p += (size_t)100352 * 512 * 2;   // yw / attn_out / h_ln2
    u16* bufB  = (u16*)p;                                   // qkv chunk / fc1 chunk

    const size_t fixed = ((size_t)786432 + 262144 + 1048576 + 1048576) * 2
                       + (size_t)262144 * 4 + (size_t)100352 * 512 * 2;
    const int nch = (ws_size >= fixed + (size_t)50176 * 2048 * 2) ? 2 : 4;
    const int chM = 100352 / nch;          // rows per chunk (multiple of 256 and 49)
    const int chWB = chM / 49;             // window-batches per chunk

    cvt_kernel<<<3072, 256, 0, stream>>>(qkvw, wq, 786432);
    cvt_kernel<<<1024, 256, 0, stream>>>(projw, wp, 262144);
    cvt_kernel<<<4096, 256, 0, stream>>>(fc1w, w1, 1048576);
    cvt_p64_kernel<<<4096, 256, 0, stream>>>(fc2w, w2, 1048576);
    tbl_kernel<<<1024, 256, 0, stream>>>(relb, tbl);

    // LN1 + shift + window partition -> bufA (bf16, window layout)
    ln_kernel<true><<<25088, 256, 0, stream>>>(x, n1g, n1b, bufA);

    // QKV + attention, chunked
    for (int c = 0; c < nch; ++c) {
        const u16* Ach = bufA + (size_t)c * chM * 512;
        gemm6<0><<<(chM >> 8) * 6, 512, 0, stream>>>(Ach, wq, qkvb, chM, 1536, 512, bufB, nullptr);
        attn_kernel<<<chWB * 16, 256, 0, stream>>>(bufB, tbl, bufA, c * chWB);
    }

    // proj + window-reverse + unshift + residual -> d_out (x2, fp32)
    gemm6<2><<<392 * 2, 512, 0, stream>>>(bufA, wp, projb, 100352, 512, 512, out, x);

    // LN2 -> bufA (bf16)
    ln_kernel<false><<<25088, 256, 0, stream>>>(out, n2g, n2b, bufA);

    // MLP, chunked; fc2 accumulates into d_out
    for (int c = 0; c < nch; ++c) {
        const u16* Ach = bufA + (size_t)c * chM * 512;
        float* Och = out + (size_t)c * chM * 512;
        gemm6<1><<<(chM >> 8) * 8, 512, 0, stream>>>(Ach, w1, fc1b, chM, 2048, 512, bufB, nullptr);
        gemm6<3><<<(chM >> 8) * 2, 512, 0, stream>>>(bufB, w2, fc2b, chM, 512, 2048, Och, nullptr);
    }
}